// Round 12
// baseline (727.089 us; speedup 1.0000x reference)
//
#include <hip/hip_runtime.h>
#include <hip/hip_bf16.h>
#include <cmath>

#define SLOPE 0.2f

typedef __attribute__((ext_vector_type(8))) short bf16x8;
typedef __attribute__((ext_vector_type(4))) float f32x4;
typedef __attribute__((ext_vector_type(2))) float f32x2;

union bfpack { bf16x8 v; unsigned int u[4]; };

__device__ __forceinline__ unsigned short bf16_rne(float x) {
    unsigned int b = __float_as_uint(x);
    b += 0x7FFFu + ((b >> 16) & 1u);
    return (unsigned short)(b >> 16);
}
__device__ __forceinline__ float bf16_tof(unsigned short h) {
    return __uint_as_float(((unsigned int)h) << 16);
}
__device__ __forceinline__ f32x2 splat2(float s) { return (f32x2){s, s}; }

__device__ __forceinline__ long long pack_pair(int s, int e) {
    return (long long)(((unsigned long long)(unsigned)e << 32) | (unsigned)s);
}

// sum over 16-lane groups entirely in the VALU via DPP (no ds_bpermute)
__device__ __forceinline__ float dpp_red16(float x) {
    int y;
    y = __builtin_amdgcn_update_dpp(0, __float_as_int(x), 0xB1, 0xF, 0xF, true);
    x += __int_as_float(y);
    y = __builtin_amdgcn_update_dpp(0, __float_as_int(x), 0x4E, 0xF, 0xF, true);
    x += __int_as_float(y);
    y = __builtin_amdgcn_update_dpp(0, __float_as_int(x), 0x141, 0xF, 0xF, true);
    x += __int_as_float(y);
    y = __builtin_amdgcn_update_dpp(0, __float_as_int(x), 0x140, 0xF, 0xF, true);
    x += __int_as_float(y);
    return x;
}

// ---------------------------------------------------------------- preprocessing

__global__ __launch_bounds__(256) void count_deg_kernel(
    const int* __restrict__ dstv, int* __restrict__ deg, int E)
{
    int base = (blockIdx.x * 256 + threadIdx.x) * 4;
    if (base >= E) return;
    if (base + 4 <= E) {
        int4 d4 = *(const int4*)&dstv[base];
        atomicAdd(&deg[d4.x], 1);
        atomicAdd(&deg[d4.y], 1);
        atomicAdd(&deg[d4.z], 1);
        atomicAdd(&deg[d4.w], 1);
    } else {
        for (int e = base; e < E; ++e) atomicAdd(&deg[dstv[e]], 1);
    }
}

// multi-block exclusive scan over (deg[i]+1), 1024 elems per block
__global__ __launch_bounds__(256) void scanA_kernel(
    const int* __restrict__ deg, int* __restrict__ bsum, int N)
{
    __shared__ int wsum[4];
    int t = threadIdx.x;
    int base = blockIdx.x * 1024 + t * 4;
    int s = 0;
    #pragma unroll
    for (int j = 0; j < 4; ++j) {
        int i = base + j;
        if (i < N) s += deg[i] + 1;
    }
    #pragma unroll
    for (int off = 1; off < 64; off <<= 1) s += __shfl_xor(s, off);
    if ((t & 63) == 0) wsum[t >> 6] = s;
    __syncthreads();
    if (t == 0) bsum[blockIdx.x] = wsum[0] + wsum[1] + wsum[2] + wsum[3];
}

__global__ void scanB_kernel(int* __restrict__ bsum, int nb)
{
    __shared__ int wsum[16];
    int t = threadIdx.x, lane = t & 63, w = t >> 6;
    int v = (t < nb) ? bsum[t] : 0;
    #pragma unroll
    for (int off = 1; off < 64; off <<= 1) {
        int u = __shfl_up(v, off);
        if (lane >= off) v += u;
    }
    if (lane == 63) wsum[w] = v;
    __syncthreads();
    int add = 0;
    for (int i = 0; i < w; ++i) add += wsum[i];
    v += add;
    if (t < nb) bsum[t] = v;
}

__global__ __launch_bounds__(256) void scanC_kernel(
    const int* __restrict__ deg, const int* __restrict__ bsum,
    int* __restrict__ rowptr, int N)
{
    __shared__ int wsum[4];
    int t = threadIdx.x, lane = t & 63, w = t >> 6;
    int base = blockIdx.x * 1024 + t * 4;
    int v[4];
    int s = 0;
    #pragma unroll
    for (int j = 0; j < 4; ++j) {
        int i = base + j;
        v[j] = (i < N) ? (deg[i] + 1) : 0;
        s += v[j];
    }
    int incl = s;
    #pragma unroll
    for (int off = 1; off < 64; off <<= 1) {
        int u = __shfl_up(incl, off);
        if (lane >= off) incl += u;
    }
    if (lane == 63) wsum[w] = incl;
    __syncthreads();
    int wadd = 0;
    for (int i = 0; i < w; ++i) wadd += wsum[i];
    int boff = blockIdx.x ? bsum[blockIdx.x - 1] : 0;
    int running = boff + wadd + (incl - s);
    #pragma unroll
    for (int j = 0; j < 4; ++j) {
        int i = base + j;
        running += v[j];
        if (i < N) rowptr[i + 1] = running;
    }
    if (blockIdx.x == 0 && t == 0) rowptr[0] = 0;
}

// scatter packed 8B {src, eid} per edge; 4 edges/thread so the 4 atomic
// round-trips overlap; nontemporal stores for the random scatter.
__global__ __launch_bounds__(256) void fill_csr_kernel(
    const int* __restrict__ srcv, const int* __restrict__ dstv,
    const int* __restrict__ rowptr, int* __restrict__ fill,
    long long* __restrict__ pairs, int E)
{
    int base = (blockIdx.x * 256 + threadIdx.x) * 4;
    if (base >= E) return;
    if (base + 4 <= E) {
        int4 d4 = *(const int4*)&dstv[base];
        int4 s4 = *(const int4*)&srcv[base];
        int d[4] = {d4.x, d4.y, d4.z, d4.w};
        int s[4] = {s4.x, s4.y, s4.z, s4.w};
        int pos[4];
        #pragma unroll
        for (int j = 0; j < 4; ++j)
            pos[j] = rowptr[d[j]] + atomicAdd(&fill[d[j]], 1);
        #pragma unroll
        for (int j = 0; j < 4; ++j)
            __builtin_nontemporal_store(pack_pair(s[j], base + j), &pairs[pos[j]]);
    } else {
        for (int e = base; e < E; ++e) {
            int d = dstv[e];
            int pos = rowptr[d] + atomicAdd(&fill[d], 1);
            __builtin_nontemporal_store(pack_pair(srcv[e], e), &pairs[pos]);
        }
    }
}

// linear over slots: unpack pairs, gather eattr (random READ, L3-served),
// write col + eattr_perm linearly. Self-loop slots hold stale pairs: clamp
// the id (harmless read) — selfloop_kernel overwrites them after.
__global__ __launch_bounds__(256) void gather_perm_kernel(
    const long long* __restrict__ pairs, const float* __restrict__ eattr,
    int* __restrict__ col, float* __restrict__ eattr_perm, int Etot, int E)
{
    int p = blockIdx.x * 256 + threadIdx.x;
    if (p >= Etot) return;
    long long pr = pairs[p];
    col[p] = (int)(unsigned)(pr & 0xFFFFFFFFll);
    unsigned id = (unsigned)((unsigned long long)pr >> 32);
    if (id >= (unsigned)E) id = 0;
    *(float4*)&eattr_perm[(size_t)p * 4] = *(const float4*)&eattr[(size_t)id * 4];
}

__global__ __launch_bounds__(256) void selfloop_kernel(
    const int* __restrict__ rowptr, const int* __restrict__ deg,
    int* __restrict__ col, float* __restrict__ eattr_perm, int N)
{
    int n = blockIdx.x * 256 + threadIdx.x;
    if (n >= N) return;
    int e0 = rowptr[n], e1 = rowptr[n + 1];
    float4 s = make_float4(0.f, 0.f, 0.f, 0.f);
    for (int e = e0; e < e1 - 1; ++e) {
        float4 a = *(const float4*)&eattr_perm[(size_t)e * 4];
        s.x += a.x; s.y += a.y; s.z += a.z; s.w += a.w;
    }
    float inv = 1.0f / fmaxf((float)deg[n], 1.0f);
    s.x *= inv; s.y *= inv; s.z *= inv; s.w *= inv;
    int pos = e1 - 1;
    col[pos] = n;
    *(float4*)&eattr_perm[(size_t)pos * 4] = s;
}

// W prep: Thi/Tlo[c][k] = bf16 hi/lo split of W[k][c], c in [0,256) = Wl|Wr.
__global__ __launch_bounds__(128) void wprep_kernel(
    const float* __restrict__ Wl, const float* __restrict__ Wr,
    unsigned short* __restrict__ Thi, unsigned short* __restrict__ Tlo)
{
    int c = blockIdx.x;      // 0..255
    int k = threadIdx.x;     // 0..127
    const float* W = (c < 128) ? Wl : Wr;
    float v = W[(size_t)k * 128 + (c & 127)];
    unsigned short h = bf16_rne(v);
    float lo = v - bf16_tof(h);
    Thi[(size_t)c * 128 + k] = h;
    Tlo[(size_t)c * 128 + k] = bf16_rne(lo);
}

// ---------------------------------------------------------------- MFMA GEMM (bf16x3)
__global__ __launch_bounds__(256, 4) void gemm_mfma_kernel(
    const float* __restrict__ H,
    const unsigned short* __restrict__ Thi, const unsigned short* __restrict__ Tlo,
    unsigned short* __restrict__ XLH, unsigned short* __restrict__ XRH, int nrows)
{
    __shared__ unsigned short sHi[32 * 128];
    __shared__ unsigned short sLo[32 * 128];
    int t = threadIdx.x;
    int r0 = blockIdx.x * 32;

    #pragma unroll
    for (int i = 0; i < 2; ++i) {
        int idx = t + i * 256;           // 512 = 32 rows * 16 chunks
        int row = idx >> 4, chunk = idx & 15;
        int gr = min(r0 + row, nrows - 1);
        float4 a = *(const float4*)&H[(size_t)gr * 128 + chunk * 8];
        float4 b = *(const float4*)&H[(size_t)gr * 128 + chunk * 8 + 4];
        float v[8] = {a.x, a.y, a.z, a.w, b.x, b.y, b.z, b.w};
        union { bf16x8 v; unsigned short u[8]; } hv, lv;
        #pragma unroll
        for (int j = 0; j < 8; ++j) {
            unsigned short h = bf16_rne(v[j]);
            hv.u[j] = h;
            lv.u[j] = bf16_rne(v[j] - bf16_tof(h));
        }
        int slot = chunk ^ (row & 7);
        *(bf16x8*)&sHi[row * 128 + slot * 8] = hv.v;
        *(bf16x8*)&sLo[row * 128 + slot * 8] = lv.v;
    }
    __syncthreads();

    int w  = t >> 6;
    int l  = t & 63;
    int lr = l & 15;
    int lk = l >> 4;
    int cbase = w * 64;

    f32x4 acc[2][4];
    #pragma unroll
    for (int i = 0; i < 2; ++i)
        #pragma unroll
        for (int j = 0; j < 4; ++j)
            acc[i][j] = (f32x4){0.f, 0.f, 0.f, 0.f};

    #pragma unroll
    for (int k0 = 0; k0 < 128; k0 += 32) {
        bf16x8 ah[2], al[2];
        #pragma unroll
        for (int rt = 0; rt < 2; ++rt) {
            int row = rt * 16 + lr;
            int chunk = (k0 >> 3) + lk;
            int slot = chunk ^ (row & 7);
            ah[rt] = *(const bf16x8*)&sHi[row * 128 + slot * 8];
            al[rt] = *(const bf16x8*)&sLo[row * 128 + slot * 8];
        }
        int k = k0 + lk * 8;
        #pragma unroll
        for (int ct = 0; ct < 4; ++ct) {
            int c = cbase + ct * 16 + lr;
            bf16x8 bh = *(const bf16x8*)&Thi[(size_t)c * 128 + k];
            bf16x8 bl = *(const bf16x8*)&Tlo[(size_t)c * 128 + k];
            #pragma unroll
            for (int rt = 0; rt < 2; ++rt) {
                acc[rt][ct] = __builtin_amdgcn_mfma_f32_16x16x32_bf16(ah[rt], bh, acc[rt][ct], 0, 0, 0);
                acc[rt][ct] = __builtin_amdgcn_mfma_f32_16x16x32_bf16(al[rt], bh, acc[rt][ct], 0, 0, 0);
                acc[rt][ct] = __builtin_amdgcn_mfma_f32_16x16x32_bf16(ah[rt], bl, acc[rt][ct], 0, 0, 0);
            }
        }
    }

    unsigned short* OUT = (w < 2) ? XLH : XRH;
    int ccol0 = (cbase & 127);
    #pragma unroll
    for (int rt = 0; rt < 2; ++rt)
        #pragma unroll
        for (int ct = 0; ct < 4; ++ct) {
            int cc = ccol0 + ct * 16 + lr;
            #pragma unroll
            for (int q = 0; q < 4; ++q) {
                int r = r0 + rt * 16 + lk * 4 + q;
                if (r < nrows) OUT[(size_t)r * 128 + cc] = bf16_rne(acc[rt][ct][q]);
            }
        }
}

// ---------------------------------------------------------------- fused GATv2 attention + aggregation
// wave = 4 consecutive nodes; 4 edges in flight (16 lanes/edge, 8 ch/lane);
// branchless masked edge loop (uniform trip count, clamped prefetch, invalid
// edges forced to v=-inf), manual unroll-2 A/B slots (no register rotation),
// packed-f32 math, DPP reduce, wave-uniform defer-max.
__global__ __launch_bounds__(256) void gat_agg_kernel(
    const unsigned short* __restrict__ xlh, const unsigned short* __restrict__ xrh,
    const int* __restrict__ rowptr, const int* __restrict__ col,
    const float* __restrict__ eattr_perm,
    const float* __restrict__ We, const float* __restrict__ att, const float* __restrict__ bias,
    float* __restrict__ out, int N, int do_relu)
{
    int w = threadIdx.x >> 6;
    int lane = threadIdx.x & 63;
    int g = lane >> 4;
    int lg = lane & 15;
    int c0 = lg * 8;

    f32x2 at2[4], we2[4][4];
    #pragma unroll
    for (int p = 0; p < 4; ++p) at2[p] = (f32x2){att[c0 + 2 * p], att[c0 + 2 * p + 1]};
    #pragma unroll
    for (int k = 0; k < 4; ++k)
        #pragma unroll
        for (int p = 0; p < 4; ++p)
            we2[k][p] = (f32x2){We[k * 128 + c0 + 2 * p], We[k * 128 + c0 + 2 * p + 1]};

    int nbase = (blockIdx.x * 4 + w) * 4;
    if (nbase >= N) return;

    int rptr[5];
    #pragma unroll
    for (int j = 0; j < 5; ++j) rptr[j] = rowptr[min(nbase + j, N)];

    #pragma unroll 1
    for (int i = 0; i < 4; ++i) {
        int n = nbase + i;
        int nc = min(n, N - 1);

        f32x2 xr2[4];
        {
            bfpack xrp;
            xrp.v = *(const bf16x8*)&xrh[((size_t)nc << 7) + c0];
            #pragma unroll
            for (int p = 0; p < 4; ++p) {
                unsigned int u = xrp.u[p];
                xr2[p] = (f32x2){__uint_as_float(u << 16), __uint_as_float(u & 0xffff0000u)};
            }
        }

        int e0 = rptr[i], e1 = rptr[i + 1];
        int elim = e1 - 1;
        int iters = (e1 - e0 + 3) >> 2;   // >=1 (self-loop); wave-uniform

        float m = -INFINITY, den = 0.f;
        f32x2 acc2[4];
        #pragma unroll
        for (int p = 0; p < 4; ++p) acc2[p] = (f32x2){0.f, 0.f};

        auto process = [&](const float4& ea, const bfpack& xv, bool valid) {
            f32x2 xl2[4];
            #pragma unroll
            for (int p = 0; p < 4; ++p) {
                unsigned int u = xv.u[p];
                xl2[p] = (f32x2){__uint_as_float(u << 16), __uint_as_float(u & 0xffff0000u)};
            }
            f32x2 vd = (f32x2){0.f, 0.f};
            #pragma unroll
            for (int p = 0; p < 4; ++p) {
                f32x2 z = xl2[p] + xr2[p];
                z += splat2(ea.x) * we2[0][p];
                z += splat2(ea.y) * we2[1][p];
                z += splat2(ea.z) * we2[2][p];
                z += splat2(ea.w) * we2[3][p];
                f32x2 zs = splat2(SLOPE) * z;
                f32x2 lz = (f32x2){fmaxf(z.x, zs.x), fmaxf(z.y, zs.y)};
                vd += lz * at2[p];
            }
            float v = dpp_red16(vd.x + vd.y);
            v = valid ? v : -INFINITY;       // masked edge: exp->0, max->noop
            bool trig = (v - m > 8.0f);
            if (__any(trig)) {
                float mnew  = fmaxf(m, v);
                float scale = __expf(m - mnew);
                float wgt   = __expf(v - mnew);
                den = den * scale + wgt;
                #pragma unroll
                for (int p = 0; p < 4; ++p)
                    acc2[p] = acc2[p] * splat2(scale) + splat2(wgt) * xl2[p];
                m = mnew;
            } else {
                float wgt = __expf(v - m);
                den += wgt;
                #pragma unroll
                for (int p = 0; p < 4; ++p) acc2[p] += splat2(wgt) * xl2[p];
            }
        };

        int e = e0 + g;
        // prime slot A with edge e (clamped addresses are always valid)
        int ec = min(e, elim);
        int cc = col[ec];
        int cA = col[min(e + 4, elim)];
        float4 eaA = *(const float4*)&eattr_perm[(size_t)ec * 4];
        bfpack xlA;
        xlA.v = *(const bf16x8*)&xlh[((size_t)(unsigned)cc << 7) + c0];
        float4 eaB;
        bfpack xlB;

        int it = 0;
        for (; it + 2 <= iters; it += 2) {
            int enc = min(e + 4, elim);
            eaB = *(const float4*)&eattr_perm[(size_t)enc * 4];
            xlB.v = *(const bf16x8*)&xlh[((size_t)(unsigned)cA << 7) + c0];
            cA = col[min(e + 8, elim)];
            process(eaA, xlA, e < e1);
            e += 4;

            enc = min(e + 4, elim);
            eaA = *(const float4*)&eattr_perm[(size_t)enc * 4];
            xlA.v = *(const bf16x8*)&xlh[((size_t)(unsigned)cA << 7) + c0];
            cA = col[min(e + 8, elim)];
            process(eaB, xlB, e < e1);
            e += 4;
        }
        if (it < iters) process(eaA, xlA, e < e1);

        // combine 4 groups (differing running maxima)
        float M = fmaxf(m, __shfl_xor(m, 16));
        M = fmaxf(M, __shfl_xor(M, 32));
        float sc = __expf(m - M);        // 0 for empty groups (m=-inf)
        float d2 = den * sc;
        d2 += __shfl_xor(d2, 16);
        d2 += __shfl_xor(d2, 32);
        float inv = 1.f / (d2 + 1e-16f);
        float o[8];
        #pragma unroll
        for (int p = 0; p < 4; ++p) {
            float ax = acc2[p].x * sc;
            float ay = acc2[p].y * sc;
            ax += __shfl_xor(ax, 16); ax += __shfl_xor(ax, 32);
            ay += __shfl_xor(ay, 16); ay += __shfl_xor(ay, 32);
            o[2 * p] = ax * inv;
            o[2 * p + 1] = ay * inv;
        }
        if (n < N && g == 0) {
            #pragma unroll
            for (int j = 0; j < 8; ++j) {
                float val = o[j] + bias[c0 + j];
                o[j] = do_relu ? fmaxf(val, 0.f) : val;
            }
            *(float4*)&out[((size_t)n << 7) + c0]     = make_float4(o[0], o[1], o[2], o[3]);
            *(float4*)&out[((size_t)n << 7) + c0 + 4] = make_float4(o[4], o[5], o[6], o[7]);
        }
    }
}

// ---------------------------------------------------------------- launch

static inline char* carve(char*& p, size_t bytes) {
    char* r = p;
    p += (bytes + 255) & ~(size_t)255;
    return r;
}

extern "C" void kernel_launch(void* const* d_in, const int* in_sizes, int n_in,
                              void* d_out, int out_size, void* d_ws, size_t ws_size,
                              hipStream_t stream)
{
    const int* edge_index = (const int*)d_in[0];
    int E = in_sizes[0] / 2;
    int N = in_sizes[2] / 128;
    const int* srcv = edge_index;
    const int* dstv = edge_index + E;
    const float* eattr = (const float*)d_in[1];
    const float* x = (const float*)d_in[2];

    char* p = (char*)d_ws;
    int*   deg    = (int*)  carve(p, (size_t)N * 4);
    int*   fill   = (int*)  carve(p, (size_t)N * 4);
    int*   rowptr = (int*)  carve(p, (size_t)(N + 1) * 4);
    int*   bsum   = (int*)  carve(p, (size_t)1024 * 4);
    int*   col    = (int*)  carve(p, (size_t)(E + N) * 4);
    float* eperm  = (float*)carve(p, (size_t)(E + N) * 16);
    unsigned short* xlh = (unsigned short*)carve(p, (size_t)N * 256);
    unsigned short* xrh = (unsigned short*)carve(p, (size_t)N * 256);
    unsigned short* Thi = (unsigned short*)carve(p, (size_t)3 * 256 * 128 * 2);
    unsigned short* Tlo = (unsigned short*)carve(p, (size_t)3 * 256 * 128 * 2);
    // pairs aliases xlh (dead until first gemm; (E+N)*8 = 13.6MB < N*256 = 25.6MB)
    long long* pairs = (long long*)xlh;

    hipMemsetAsync(deg,  0, (size_t)N * 4, stream);
    hipMemsetAsync(fill, 0, (size_t)N * 4, stream);

    int Etot = E + N;
    int NB = (N + 1023) / 1024;
    int E4 = (E + 3) / 4;
    count_deg_kernel<<<(E4 + 255) / 256, 256, 0, stream>>>(dstv, deg, E);
    scanA_kernel<<<NB, 256, 0, stream>>>(deg, bsum, N);
    scanB_kernel<<<1, 1024, 0, stream>>>(bsum, NB);
    scanC_kernel<<<NB, 256, 0, stream>>>(deg, bsum, rowptr, N);
    fill_csr_kernel<<<(E4 + 255) / 256, 256, 0, stream>>>(srcv, dstv, rowptr, fill, pairs, E);
    gather_perm_kernel<<<(Etot + 255) / 256, 256, 0, stream>>>(pairs, eattr, col, eperm, Etot, E);
    selfloop_kernel<<<(N + 255) / 256, 256, 0, stream>>>(rowptr, deg, col, eperm, N);

    for (int li = 0; li < 3; ++li) {
        const float* Wl = (const float*)d_in[3 + 5 * li + 0];
        const float* Wr = (const float*)d_in[3 + 5 * li + 1];
        wprep_kernel<<<256, 128, 0, stream>>>(Wl, Wr,
                                              Thi + (size_t)li * 256 * 128,
                                              Tlo + (size_t)li * 256 * 128);
    }

    float* out = (float*)d_out;
    for (int li = 0; li < 3; ++li) {
        const float* Wep = (const float*)d_in[3 + 5 * li + 2];
        const float* atp = (const float*)d_in[3 + 5 * li + 3];
        const float* bp  = (const float*)d_in[3 + 5 * li + 4];
        const float* hin = (li == 0) ? x : out;
        gemm_mfma_kernel<<<(N + 31) / 32, 256, 0, stream>>>(
            hin, Thi + (size_t)li * 256 * 128, Tlo + (size_t)li * 256 * 128, xlh, xrh, N);
        gat_agg_kernel<<<(N + 15) / 16, 256, 0, stream>>>(xlh, xrh, rowptr, col, eperm,
                                                          Wep, atp, bp, out, N, li < 2 ? 1 : 0);
    }
}

// Round 13
// 680.669 us; speedup vs baseline: 1.0682x; 1.0682x over previous
//
#include <hip/hip_runtime.h>
#include <hip/hip_bf16.h>
#include <cmath>

#define SLOPE 0.2f
#define CH 8192
#define BSH 8

typedef __attribute__((ext_vector_type(8))) short bf16x8;
typedef __attribute__((ext_vector_type(4))) float f32x4;
typedef __attribute__((ext_vector_type(2))) float f32x2;

union bfpack { bf16x8 v; unsigned int u[4]; };

__device__ __forceinline__ unsigned short bf16_rne(float x) {
    unsigned int b = __float_as_uint(x);
    b += 0x7FFFu + ((b >> 16) & 1u);
    return (unsigned short)(b >> 16);
}
__device__ __forceinline__ float bf16_tof(unsigned short h) {
    return __uint_as_float(((unsigned int)h) << 16);
}
__device__ __forceinline__ f32x2 splat2(float s) { return (f32x2){s, s}; }

// sum over 16-lane groups entirely in the VALU via DPP (no ds_bpermute)
__device__ __forceinline__ float dpp_red16(float x) {
    int y;
    y = __builtin_amdgcn_update_dpp(0, __float_as_int(x), 0xB1, 0xF, 0xF, true);
    x += __int_as_float(y);
    y = __builtin_amdgcn_update_dpp(0, __float_as_int(x), 0x4E, 0xF, 0xF, true);
    x += __int_as_float(y);
    y = __builtin_amdgcn_update_dpp(0, __float_as_int(x), 0x141, 0xF, 0xF, true);
    x += __int_as_float(y);
    y = __builtin_amdgcn_update_dpp(0, __float_as_int(x), 0x140, 0xF, 0xF, true);
    x += __int_as_float(y);
    return x;
}

// ---------------------------------------------------------------- preprocessing

__global__ __launch_bounds__(256) void count_deg_kernel(
    const int* __restrict__ dstv, int* __restrict__ deg, int E)
{
    int base = (blockIdx.x * 256 + threadIdx.x) * 4;
    if (base >= E) return;
    if (base + 4 <= E) {
        int4 d4 = *(const int4*)&dstv[base];
        atomicAdd(&deg[d4.x], 1);
        atomicAdd(&deg[d4.y], 1);
        atomicAdd(&deg[d4.z], 1);
        atomicAdd(&deg[d4.w], 1);
    } else {
        for (int e = base; e < E; ++e) atomicAdd(&deg[dstv[e]], 1);
    }
}

// multi-block exclusive scan over (deg[i]+1), 1024 elems per block
__global__ __launch_bounds__(256) void scanA_kernel(
    const int* __restrict__ deg, int* __restrict__ bsum, int N)
{
    __shared__ int wsum[4];
    int t = threadIdx.x;
    int base = blockIdx.x * 1024 + t * 4;
    int s = 0;
    #pragma unroll
    for (int j = 0; j < 4; ++j) {
        int i = base + j;
        if (i < N) s += deg[i] + 1;
    }
    #pragma unroll
    for (int off = 1; off < 64; off <<= 1) s += __shfl_xor(s, off);
    if ((t & 63) == 0) wsum[t >> 6] = s;
    __syncthreads();
    if (t == 0) bsum[blockIdx.x] = wsum[0] + wsum[1] + wsum[2] + wsum[3];
}

__global__ void scanB_kernel(int* __restrict__ bsum, int nb)
{
    __shared__ int wsum[16];
    int t = threadIdx.x, lane = t & 63, w = t >> 6;
    int v = (t < nb) ? bsum[t] : 0;
    #pragma unroll
    for (int off = 1; off < 64; off <<= 1) {
        int u = __shfl_up(v, off);
        if (lane >= off) v += u;
    }
    if (lane == 63) wsum[w] = v;
    __syncthreads();
    int add = 0;
    for (int i = 0; i < w; ++i) add += wsum[i];
    v += add;
    if (t < nb) bsum[t] = v;
}

__global__ __launch_bounds__(256) void scanC_kernel(
    const int* __restrict__ deg, const int* __restrict__ bsum,
    int* __restrict__ rowptr, int N)
{
    __shared__ int wsum[4];
    int t = threadIdx.x, lane = t & 63, w = t >> 6;
    int base = blockIdx.x * 1024 + t * 4;
    int v[4];
    int s = 0;
    #pragma unroll
    for (int j = 0; j < 4; ++j) {
        int i = base + j;
        v[j] = (i < N) ? (deg[i] + 1) : 0;
        s += v[j];
    }
    int incl = s;
    #pragma unroll
    for (int off = 1; off < 64; off <<= 1) {
        int u = __shfl_up(incl, off);
        if (lane >= off) incl += u;
    }
    if (lane == 63) wsum[w] = incl;
    __syncthreads();
    int wadd = 0;
    for (int i = 0; i < w; ++i) wadd += wsum[i];
    int boff = blockIdx.x ? bsum[blockIdx.x - 1] : 0;
    int running = boff + wadd + (incl - s);
    #pragma unroll
    for (int j = 0; j < 4; ++j) {
        int i = base + j;
        running += v[j];
        if (i < N) rowptr[i + 1] = running;
    }
    if (blockIdx.x == 0 && t == 0) rowptr[0] = 0;
}

// -------- two-level counting sort of edges by dst --------
// coarse: bin CH edges/block by bucket=dst>>8 in LDS, flush contiguous runs
// to globally-reserved ranges (mostly-full cachelines, coalesced).
__global__ __launch_bounds__(256, 2) void bin_coarse_kernel(
    const int* __restrict__ srcv, const int* __restrict__ dstv,
    const int* __restrict__ rowptr, int* __restrict__ gfill,
    unsigned long long* __restrict__ coarse, int E, int N, int nbuckets, int sb)
{
    __shared__ unsigned long long recs[CH];
    __shared__ int lcount[512];
    __shared__ int loffs[512];
    __shared__ int gpos[512];
    __shared__ int cbase[512];
    int t = threadIdx.x;
    int base = blockIdx.x * CH;
    int count = min(CH, E - base);

    for (int b = t; b < 512; b += 256) lcount[b] = 0;
    __syncthreads();

    int rank[CH / 256];
    #pragma unroll
    for (int i = 0; i < CH / 256; ++i) {
        int j = i * 256 + t;
        if (j < count) {
            int d = dstv[base + j];
            rank[i] = atomicAdd(&lcount[d >> BSH], 1);
        }
    }
    __syncthreads();

    // inclusive Hillis-Steele scan of lcount into loffs (512 wide)
    loffs[t] = lcount[t];
    loffs[t + 256] = lcount[t + 256];
    __syncthreads();
    for (int off = 1; off < 512; off <<= 1) {
        int i0 = t, i1 = t + 256;
        int v0 = (i0 >= off) ? loffs[i0 - off] : 0;
        int v1 = (i1 >= off) ? loffs[i1 - off] : 0;
        __syncthreads();
        loffs[i0] += v0;
        loffs[i1] += v1;
        __syncthreads();
    }

    // place records at scan offsets (sorted by bucket within LDS)
    #pragma unroll
    for (int i = 0; i < CH / 256; ++i) {
        int j = i * 256 + t;
        if (j < count) {
            int e = base + j;
            int d = dstv[e];
            int s = srcv[e];
            int b = d >> BSH;
            int slot = loffs[b] - lcount[b] + rank[i];
            recs[slot] = (unsigned long long)(unsigned)s
                       | ((unsigned long long)(unsigned)d << sb)
                       | ((unsigned long long)(unsigned)e << (2 * sb));
        }
    }
    // reserve global ranges + preload coarse bases
    __syncthreads();
    for (int b = t; b < nbuckets; b += 256) {
        int c = lcount[b];
        gpos[b] = c ? atomicAdd(&gfill[b], c) : 0;
        cbase[b] = rowptr[min(b << BSH, N)];
    }
    __syncthreads();
    // flush: consecutive LDS slots -> consecutive global addrs per bucket run
    int dmask = (1 << sb) - 1;
    for (int j = t; j < count; j += 256) {
        unsigned long long r = recs[j];
        int d = (int)((r >> sb) & dmask);
        int b = d >> BSH;
        int excl = loffs[b] - lcount[b];
        __builtin_nontemporal_store(r, &coarse[(size_t)cbase[b] + gpos[b] + (j - excl)]);
    }
}

// fine: one block per bucket; scatter within L2-resident region via LDS
// counters; writes col + gathers eattr directly (gather_perm eliminated).
__global__ __launch_bounds__(256) void bin_fine_kernel(
    const unsigned long long* __restrict__ coarse, const int* __restrict__ gfill,
    const int* __restrict__ rowptr, const float* __restrict__ eattr,
    int* __restrict__ col, float* __restrict__ eattr_perm, int N, int sb)
{
    __shared__ int lfill[256];
    __shared__ int lrow[257];
    int b = blockIdx.x;
    int t = threadIdx.x;
    int n0 = b << BSH;
    lfill[t] = 0;
    lrow[t] = rowptr[min(n0 + t, N)];
    if (t == 0) lrow[256] = rowptr[min(n0 + 256, N)];
    __syncthreads();
    int cb = lrow[0];
    int cnt = gfill[b];
    int dmask = (1 << sb) - 1;
    for (int j = t; j < cnt; j += 256) {
        unsigned long long r = coarse[(size_t)cb + j];
        int s = (int)(r & dmask);
        int d = (int)((r >> sb) & dmask);
        unsigned e = (unsigned)(r >> (2 * sb));
        int local = d & ((1 << BSH) - 1);
        int pos = lrow[local] + atomicAdd(&lfill[local], 1);
        col[pos] = s;
        *(float4*)&eattr_perm[(size_t)pos * 4] = *(const float4*)&eattr[(size_t)e * 4];
    }
}

__global__ __launch_bounds__(256) void selfloop_kernel(
    const int* __restrict__ rowptr, const int* __restrict__ deg,
    int* __restrict__ col, float* __restrict__ eattr_perm, int N)
{
    int n = blockIdx.x * 256 + threadIdx.x;
    if (n >= N) return;
    int e0 = rowptr[n], e1 = rowptr[n + 1];
    float4 s = make_float4(0.f, 0.f, 0.f, 0.f);
    for (int e = e0; e < e1 - 1; ++e) {
        float4 a = *(const float4*)&eattr_perm[(size_t)e * 4];
        s.x += a.x; s.y += a.y; s.z += a.z; s.w += a.w;
    }
    float inv = 1.0f / fmaxf((float)deg[n], 1.0f);
    s.x *= inv; s.y *= inv; s.z *= inv; s.w *= inv;
    int pos = e1 - 1;
    col[pos] = n;
    *(float4*)&eattr_perm[(size_t)pos * 4] = s;
}

// W prep: Thi/Tlo[c][k] = bf16 hi/lo split of W[k][c], c in [0,256) = Wl|Wr.
__global__ __launch_bounds__(128) void wprep_kernel(
    const float* __restrict__ Wl, const float* __restrict__ Wr,
    unsigned short* __restrict__ Thi, unsigned short* __restrict__ Tlo)
{
    int c = blockIdx.x;
    int k = threadIdx.x;
    const float* W = (c < 128) ? Wl : Wr;
    float v = W[(size_t)k * 128 + (c & 127)];
    unsigned short h = bf16_rne(v);
    float lo = v - bf16_tof(h);
    Thi[(size_t)c * 128 + k] = h;
    Tlo[(size_t)c * 128 + k] = bf16_rne(lo);
}

// ---------------------------------------------------------------- MFMA GEMM (bf16x3)
__global__ __launch_bounds__(256, 4) void gemm_mfma_kernel(
    const float* __restrict__ H,
    const unsigned short* __restrict__ Thi, const unsigned short* __restrict__ Tlo,
    unsigned short* __restrict__ XLH, unsigned short* __restrict__ XRH, int nrows)
{
    __shared__ unsigned short sHi[32 * 128];
    __shared__ unsigned short sLo[32 * 128];
    int t = threadIdx.x;
    int r0 = blockIdx.x * 32;

    #pragma unroll
    for (int i = 0; i < 2; ++i) {
        int idx = t + i * 256;
        int row = idx >> 4, chunk = idx & 15;
        int gr = min(r0 + row, nrows - 1);
        float4 a = *(const float4*)&H[(size_t)gr * 128 + chunk * 8];
        float4 b = *(const float4*)&H[(size_t)gr * 128 + chunk * 8 + 4];
        float v[8] = {a.x, a.y, a.z, a.w, b.x, b.y, b.z, b.w};
        union { bf16x8 v; unsigned short u[8]; } hv, lv;
        #pragma unroll
        for (int j = 0; j < 8; ++j) {
            unsigned short h = bf16_rne(v[j]);
            hv.u[j] = h;
            lv.u[j] = bf16_rne(v[j] - bf16_tof(h));
        }
        int slot = chunk ^ (row & 7);
        *(bf16x8*)&sHi[row * 128 + slot * 8] = hv.v;
        *(bf16x8*)&sLo[row * 128 + slot * 8] = lv.v;
    }
    __syncthreads();

    int w  = t >> 6;
    int l  = t & 63;
    int lr = l & 15;
    int lk = l >> 4;
    int cbase = w * 64;

    f32x4 acc[2][4];
    #pragma unroll
    for (int i = 0; i < 2; ++i)
        #pragma unroll
        for (int j = 0; j < 4; ++j)
            acc[i][j] = (f32x4){0.f, 0.f, 0.f, 0.f};

    #pragma unroll
    for (int k0 = 0; k0 < 128; k0 += 32) {
        bf16x8 ah[2], al[2];
        #pragma unroll
        for (int rt = 0; rt < 2; ++rt) {
            int row = rt * 16 + lr;
            int chunk = (k0 >> 3) + lk;
            int slot = chunk ^ (row & 7);
            ah[rt] = *(const bf16x8*)&sHi[row * 128 + slot * 8];
            al[rt] = *(const bf16x8*)&sLo[row * 128 + slot * 8];
        }
        int k = k0 + lk * 8;
        #pragma unroll
        for (int ct = 0; ct < 4; ++ct) {
            int c = cbase + ct * 16 + lr;
            bf16x8 bh = *(const bf16x8*)&Thi[(size_t)c * 128 + k];
            bf16x8 bl = *(const bf16x8*)&Tlo[(size_t)c * 128 + k];
            #pragma unroll
            for (int rt = 0; rt < 2; ++rt) {
                acc[rt][ct] = __builtin_amdgcn_mfma_f32_16x16x32_bf16(ah[rt], bh, acc[rt][ct], 0, 0, 0);
                acc[rt][ct] = __builtin_amdgcn_mfma_f32_16x16x32_bf16(al[rt], bh, acc[rt][ct], 0, 0, 0);
                acc[rt][ct] = __builtin_amdgcn_mfma_f32_16x16x32_bf16(ah[rt], bl, acc[rt][ct], 0, 0, 0);
            }
        }
    }

    unsigned short* OUT = (w < 2) ? XLH : XRH;
    int ccol0 = (cbase & 127);
    #pragma unroll
    for (int rt = 0; rt < 2; ++rt)
        #pragma unroll
        for (int ct = 0; ct < 4; ++ct) {
            int cc = ccol0 + ct * 16 + lr;
            #pragma unroll
            for (int q = 0; q < 4; ++q) {
                int r = r0 + rt * 16 + lk * 4 + q;
                if (r < nrows) OUT[(size_t)r * 128 + cc] = bf16_rne(acc[rt][ct][q]);
            }
        }
}

// ---------------------------------------------------------------- fused GATv2 attention + aggregation
__global__ __launch_bounds__(256) void gat_agg_kernel(
    const unsigned short* __restrict__ xlh, const unsigned short* __restrict__ xrh,
    const int* __restrict__ rowptr, const int* __restrict__ col,
    const float* __restrict__ eattr_perm,
    const float* __restrict__ We, const float* __restrict__ att, const float* __restrict__ bias,
    float* __restrict__ out, int N, int do_relu)
{
    int w = threadIdx.x >> 6;
    int lane = threadIdx.x & 63;
    int g = lane >> 4;
    int lg = lane & 15;
    int c0 = lg * 8;

    f32x2 at2[4], we2[4][4];
    #pragma unroll
    for (int p = 0; p < 4; ++p) at2[p] = (f32x2){att[c0 + 2 * p], att[c0 + 2 * p + 1]};
    #pragma unroll
    for (int k = 0; k < 4; ++k)
        #pragma unroll
        for (int p = 0; p < 4; ++p)
            we2[k][p] = (f32x2){We[k * 128 + c0 + 2 * p], We[k * 128 + c0 + 2 * p + 1]};

    int nbase = (blockIdx.x * 4 + w) * 4;
    if (nbase >= N) return;

    int rptr[5];
    #pragma unroll
    for (int j = 0; j < 5; ++j) rptr[j] = rowptr[min(nbase + j, N)];

    #pragma unroll 1
    for (int i = 0; i < 4; ++i) {
        int n = nbase + i;
        int nc = min(n, N - 1);

        f32x2 xr2[4];
        {
            bfpack xrp;
            xrp.v = *(const bf16x8*)&xrh[((size_t)nc << 7) + c0];
            #pragma unroll
            for (int p = 0; p < 4; ++p) {
                unsigned int u = xrp.u[p];
                xr2[p] = (f32x2){__uint_as_float(u << 16), __uint_as_float(u & 0xffff0000u)};
            }
        }

        int e0 = rptr[i], e1 = rptr[i + 1];
        int elim = e1 - 1;
        int iters = (e1 - e0 + 3) >> 2;

        float m = -INFINITY, den = 0.f;
        f32x2 acc2[4];
        #pragma unroll
        for (int p = 0; p < 4; ++p) acc2[p] = (f32x2){0.f, 0.f};

        auto process = [&](const float4& ea, const bfpack& xv, bool valid) {
            f32x2 xl2[4];
            #pragma unroll
            for (int p = 0; p < 4; ++p) {
                unsigned int u = xv.u[p];
                xl2[p] = (f32x2){__uint_as_float(u << 16), __uint_as_float(u & 0xffff0000u)};
            }
            f32x2 vd = (f32x2){0.f, 0.f};
            #pragma unroll
            for (int p = 0; p < 4; ++p) {
                f32x2 z = xl2[p] + xr2[p];
                z += splat2(ea.x) * we2[0][p];
                z += splat2(ea.y) * we2[1][p];
                z += splat2(ea.z) * we2[2][p];
                z += splat2(ea.w) * we2[3][p];
                f32x2 zs = splat2(SLOPE) * z;
                f32x2 lz = (f32x2){fmaxf(z.x, zs.x), fmaxf(z.y, zs.y)};
                vd += lz * at2[p];
            }
            float v = dpp_red16(vd.x + vd.y);
            v = valid ? v : -INFINITY;
            bool trig = (v - m > 8.0f);
            if (__any(trig)) {
                float mnew  = fmaxf(m, v);
                float scale = __expf(m - mnew);
                float wgt   = __expf(v - mnew);
                den = den * scale + wgt;
                #pragma unroll
                for (int p = 0; p < 4; ++p)
                    acc2[p] = acc2[p] * splat2(scale) + splat2(wgt) * xl2[p];
                m = mnew;
            } else {
                float wgt = __expf(v - m);
                den += wgt;
                #pragma unroll
                for (int p = 0; p < 4; ++p) acc2[p] += splat2(wgt) * xl2[p];
            }
        };

        int e = e0 + g;
        int ec = min(e, elim);
        int cc = col[ec];
        int cA = col[min(e + 4, elim)];
        float4 eaA = *(const float4*)&eattr_perm[(size_t)ec * 4];
        bfpack xlA;
        xlA.v = *(const bf16x8*)&xlh[((size_t)(unsigned)cc << 7) + c0];
        float4 eaB;
        bfpack xlB;

        int it = 0;
        for (; it + 2 <= iters; it += 2) {
            int enc = min(e + 4, elim);
            eaB = *(const float4*)&eattr_perm[(size_t)enc * 4];
            xlB.v = *(const bf16x8*)&xlh[((size_t)(unsigned)cA << 7) + c0];
            cA = col[min(e + 8, elim)];
            process(eaA, xlA, e < e1);
            e += 4;

            enc = min(e + 4, elim);
            eaA = *(const float4*)&eattr_perm[(size_t)enc * 4];
            xlA.v = *(const bf16x8*)&xlh[((size_t)(unsigned)cA << 7) + c0];
            cA = col[min(e + 8, elim)];
            process(eaB, xlB, e < e1);
            e += 4;
        }
        if (it < iters) process(eaA, xlA, e < e1);

        float M = fmaxf(m, __shfl_xor(m, 16));
        M = fmaxf(M, __shfl_xor(M, 32));
        float sc = __expf(m - M);
        float d2 = den * sc;
        d2 += __shfl_xor(d2, 16);
        d2 += __shfl_xor(d2, 32);
        float inv = 1.f / (d2 + 1e-16f);
        float o[8];
        #pragma unroll
        for (int p = 0; p < 4; ++p) {
            float ax = acc2[p].x * sc;
            float ay = acc2[p].y * sc;
            ax += __shfl_xor(ax, 16); ax += __shfl_xor(ax, 32);
            ay += __shfl_xor(ay, 16); ay += __shfl_xor(ay, 32);
            o[2 * p] = ax * inv;
            o[2 * p + 1] = ay * inv;
        }
        if (n < N && g == 0) {
            #pragma unroll
            for (int j = 0; j < 8; ++j) {
                float val = o[j] + bias[c0 + j];
                o[j] = do_relu ? fmaxf(val, 0.f) : val;
            }
            *(float4*)&out[((size_t)n << 7) + c0]     = make_float4(o[0], o[1], o[2], o[3]);
            *(float4*)&out[((size_t)n << 7) + c0 + 4] = make_float4(o[4], o[5], o[6], o[7]);
        }
    }
}

// ---------------------------------------------------------------- launch

static inline char* carve(char*& p, size_t bytes) {
    char* r = p;
    p += (bytes + 255) & ~(size_t)255;
    return r;
}

extern "C" void kernel_launch(void* const* d_in, const int* in_sizes, int n_in,
                              void* d_out, int out_size, void* d_ws, size_t ws_size,
                              hipStream_t stream)
{
    const int* edge_index = (const int*)d_in[0];
    int E = in_sizes[0] / 2;
    int N = in_sizes[2] / 128;
    const int* srcv = edge_index;
    const int* dstv = edge_index + E;
    const float* eattr = (const float*)d_in[1];
    const float* x = (const float*)d_in[2];

    char* p = (char*)d_ws;
    int*   deg    = (int*)  carve(p, (size_t)N * 4);
    int*   gfill  = (int*)  carve(p, (size_t)512 * 4);
    int*   rowptr = (int*)  carve(p, (size_t)(N + 1) * 4);
    int*   bsum   = (int*)  carve(p, (size_t)1024 * 4);
    int*   col    = (int*)  carve(p, (size_t)(E + N) * 4);
    float* eperm  = (float*)carve(p, (size_t)(E + N) * 16);
    unsigned short* xlh = (unsigned short*)carve(p, (size_t)N * 256);
    unsigned short* xrh = (unsigned short*)carve(p, (size_t)N * 256);
    unsigned short* Thi = (unsigned short*)carve(p, (size_t)3 * 256 * 128 * 2);
    unsigned short* Tlo = (unsigned short*)carve(p, (size_t)3 * 256 * 128 * 2);
    // coarse record buffer aliases xlh (dead until first gemm; (E+N)*8 <= N*256)
    unsigned long long* coarse = (unsigned long long*)xlh;

    int sb = 1;
    while ((1 << sb) < N) ++sb;      // bits for src/dst fields (N=100000 -> 17)
    int nbuckets = (N + (1 << BSH) - 1) >> BSH;

    hipMemsetAsync(deg,   0, (size_t)N * 4,   stream);
    hipMemsetAsync(gfill, 0, (size_t)512 * 4, stream);

    int NB = (N + 1023) / 1024;
    int E4 = (E + 3) / 4;
    count_deg_kernel<<<(E4 + 255) / 256, 256, 0, stream>>>(dstv, deg, E);
    scanA_kernel<<<NB, 256, 0, stream>>>(deg, bsum, N);
    scanB_kernel<<<1, 1024, 0, stream>>>(bsum, NB);
    scanC_kernel<<<NB, 256, 0, stream>>>(deg, bsum, rowptr, N);
    bin_coarse_kernel<<<(E + CH - 1) / CH, 256, 0, stream>>>(
        srcv, dstv, rowptr, gfill, coarse, E, N, nbuckets, sb);
    bin_fine_kernel<<<nbuckets, 256, 0, stream>>>(
        coarse, gfill, rowptr, eattr, col, eperm, N, sb);
    selfloop_kernel<<<(N + 255) / 256, 256, 0, stream>>>(rowptr, deg, col, eperm, N);

    for (int li = 0; li < 3; ++li) {
        const float* Wl = (const float*)d_in[3 + 5 * li + 0];
        const float* Wr = (const float*)d_in[3 + 5 * li + 1];
        wprep_kernel<<<256, 128, 0, stream>>>(Wl, Wr,
                                              Thi + (size_t)li * 256 * 128,
                                              Tlo + (size_t)li * 256 * 128);
    }

    float* out = (float*)d_out;
    for (int li = 0; li < 3; ++li) {
        const float* Wep = (const float*)d_in[3 + 5 * li + 2];
        const float* atp = (const float*)d_in[3 + 5 * li + 3];
        const float* bp  = (const float*)d_in[3 + 5 * li + 4];
        const float* hin = (li == 0) ? x : out;
        gemm_mfma_kernel<<<(N + 31) / 32, 256, 0, stream>>>(
            hin, Thi + (size_t)li * 256 * 128, Tlo + (size_t)li * 256 * 128, xlh, xrh, N);
        gat_agg_kernel<<<(N + 15) / 16, 256, 0, stream>>>(xlh, xrh, rowptr, col, eperm,
                                                          Wep, atp, bp, out, N, li < 2 ? 1 : 0);
    }
}

// Round 14
// 662.322 us; speedup vs baseline: 1.0978x; 1.0277x over previous
//
#include <hip/hip_runtime.h>
#include <hip/hip_bf16.h>
#include <cmath>

#define SLOPE 0.2f
#define CH 8192
#define BSH 8

typedef __attribute__((ext_vector_type(8))) short bf16x8;
typedef __attribute__((ext_vector_type(4))) float f32x4;
typedef __attribute__((ext_vector_type(2))) float f32x2;

union bfpack { bf16x8 v; unsigned int u[4]; };

__device__ __forceinline__ unsigned short bf16_rne(float x) {
    unsigned int b = __float_as_uint(x);
    b += 0x7FFFu + ((b >> 16) & 1u);
    return (unsigned short)(b >> 16);
}
__device__ __forceinline__ float bf16_tof(unsigned short h) {
    return __uint_as_float(((unsigned int)h) << 16);
}
__device__ __forceinline__ f32x2 splat2(float s) { return (f32x2){s, s}; }

// sum over 16-lane groups entirely in the VALU via DPP (no ds_bpermute)
__device__ __forceinline__ float dpp_red16(float x) {
    int y;
    y = __builtin_amdgcn_update_dpp(0, __float_as_int(x), 0xB1, 0xF, 0xF, true);
    x += __int_as_float(y);
    y = __builtin_amdgcn_update_dpp(0, __float_as_int(x), 0x4E, 0xF, 0xF, true);
    x += __int_as_float(y);
    y = __builtin_amdgcn_update_dpp(0, __float_as_int(x), 0x141, 0xF, 0xF, true);
    x += __int_as_float(y);
    y = __builtin_amdgcn_update_dpp(0, __float_as_int(x), 0x140, 0xF, 0xF, true);
    x += __int_as_float(y);
    return x;
}

// ---------------------------------------------------------------- preprocessing

__global__ __launch_bounds__(256) void count_deg_kernel(
    const int* __restrict__ dstv, int* __restrict__ deg, int E)
{
    int base = (blockIdx.x * 256 + threadIdx.x) * 4;
    if (base >= E) return;
    if (base + 4 <= E) {
        int4 d4 = *(const int4*)&dstv[base];
        atomicAdd(&deg[d4.x], 1);
        atomicAdd(&deg[d4.y], 1);
        atomicAdd(&deg[d4.z], 1);
        atomicAdd(&deg[d4.w], 1);
    } else {
        for (int e = base; e < E; ++e) atomicAdd(&deg[dstv[e]], 1);
    }
}

// multi-block exclusive scan over (deg[i]+1), 1024 elems per block
__global__ __launch_bounds__(256) void scanA_kernel(
    const int* __restrict__ deg, int* __restrict__ bsum, int N)
{
    __shared__ int wsum[4];
    int t = threadIdx.x;
    int base = blockIdx.x * 1024 + t * 4;
    int s = 0;
    #pragma unroll
    for (int j = 0; j < 4; ++j) {
        int i = base + j;
        if (i < N) s += deg[i] + 1;
    }
    #pragma unroll
    for (int off = 1; off < 64; off <<= 1) s += __shfl_xor(s, off);
    if ((t & 63) == 0) wsum[t >> 6] = s;
    __syncthreads();
    if (t == 0) bsum[blockIdx.x] = wsum[0] + wsum[1] + wsum[2] + wsum[3];
}

__global__ void scanB_kernel(int* __restrict__ bsum, int nb)
{
    __shared__ int wsum[16];
    int t = threadIdx.x, lane = t & 63, w = t >> 6;
    int v = (t < nb) ? bsum[t] : 0;
    #pragma unroll
    for (int off = 1; off < 64; off <<= 1) {
        int u = __shfl_up(v, off);
        if (lane >= off) v += u;
    }
    if (lane == 63) wsum[w] = v;
    __syncthreads();
    int add = 0;
    for (int i = 0; i < w; ++i) add += wsum[i];
    v += add;
    if (t < nb) bsum[t] = v;
}

__global__ __launch_bounds__(256) void scanC_kernel(
    const int* __restrict__ deg, const int* __restrict__ bsum,
    int* __restrict__ rowptr, int N)
{
    __shared__ int wsum[4];
    int t = threadIdx.x, lane = t & 63, w = t >> 6;
    int base = blockIdx.x * 1024 + t * 4;
    int v[4];
    int s = 0;
    #pragma unroll
    for (int j = 0; j < 4; ++j) {
        int i = base + j;
        v[j] = (i < N) ? (deg[i] + 1) : 0;
        s += v[j];
    }
    int incl = s;
    #pragma unroll
    for (int off = 1; off < 64; off <<= 1) {
        int u = __shfl_up(incl, off);
        if (lane >= off) incl += u;
    }
    if (lane == 63) wsum[w] = incl;
    __syncthreads();
    int wadd = 0;
    for (int i = 0; i < w; ++i) wadd += wsum[i];
    int boff = blockIdx.x ? bsum[blockIdx.x - 1] : 0;
    int running = boff + wadd + (incl - s);
    #pragma unroll
    for (int j = 0; j < 4; ++j) {
        int i = base + j;
        running += v[j];
        if (i < N) rowptr[i + 1] = running;
    }
    if (blockIdx.x == 0 && t == 0) rowptr[0] = 0;
}

// -------- two-level counting sort of edges by dst --------
__global__ __launch_bounds__(256, 2) void bin_coarse_kernel(
    const int* __restrict__ srcv, const int* __restrict__ dstv,
    const int* __restrict__ rowptr, int* __restrict__ gfill,
    unsigned long long* __restrict__ coarse, int E, int N, int nbuckets, int sb)
{
    __shared__ unsigned long long recs[CH];
    __shared__ int lcount[512];
    __shared__ int loffs[512];
    __shared__ int gpos[512];
    __shared__ int cbase[512];
    int t = threadIdx.x;
    int base = blockIdx.x * CH;
    int count = min(CH, E - base);

    for (int b = t; b < 512; b += 256) lcount[b] = 0;
    __syncthreads();

    int rank[CH / 256];
    #pragma unroll
    for (int i = 0; i < CH / 256; ++i) {
        int j = i * 256 + t;
        if (j < count) {
            int d = dstv[base + j];
            rank[i] = atomicAdd(&lcount[d >> BSH], 1);
        }
    }
    __syncthreads();

    loffs[t] = lcount[t];
    loffs[t + 256] = lcount[t + 256];
    __syncthreads();
    for (int off = 1; off < 512; off <<= 1) {
        int i0 = t, i1 = t + 256;
        int v0 = (i0 >= off) ? loffs[i0 - off] : 0;
        int v1 = (i1 >= off) ? loffs[i1 - off] : 0;
        __syncthreads();
        loffs[i0] += v0;
        loffs[i1] += v1;
        __syncthreads();
    }

    #pragma unroll
    for (int i = 0; i < CH / 256; ++i) {
        int j = i * 256 + t;
        if (j < count) {
            int e = base + j;
            int d = dstv[e];
            int s = srcv[e];
            int b = d >> BSH;
            int slot = loffs[b] - lcount[b] + rank[i];
            recs[slot] = (unsigned long long)(unsigned)s
                       | ((unsigned long long)(unsigned)d << sb)
                       | ((unsigned long long)(unsigned)e << (2 * sb));
        }
    }
    __syncthreads();
    for (int b = t; b < nbuckets; b += 256) {
        int c = lcount[b];
        gpos[b] = c ? atomicAdd(&gfill[b], c) : 0;
        cbase[b] = rowptr[min(b << BSH, N)];
    }
    __syncthreads();
    int dmask = (1 << sb) - 1;
    for (int j = t; j < count; j += 256) {
        unsigned long long r = recs[j];
        int d = (int)((r >> sb) & dmask);
        int b = d >> BSH;
        int excl = loffs[b] - lcount[b];
        __builtin_nontemporal_store(r, &coarse[(size_t)cbase[b] + gpos[b] + (j - excl)]);
    }
}

// fine: one block per bucket; scatter within L2-resident region via LDS
// counters; also accumulates per-node eattr sums in LDS and writes the
// self-loop slot (mean attr) at block end — selfloop kernel eliminated.
__global__ __launch_bounds__(256) void bin_fine_kernel(
    const unsigned long long* __restrict__ coarse, const int* __restrict__ gfill,
    const int* __restrict__ rowptr, const float* __restrict__ eattr,
    int* __restrict__ col, float* __restrict__ eattr_perm, int N, int sb)
{
    __shared__ int lfill[256];
    __shared__ int lrow[257];
    __shared__ float lsum[256][4];
    int b = blockIdx.x;
    int t = threadIdx.x;
    int n0 = b << BSH;
    lfill[t] = 0;
    lrow[t] = rowptr[min(n0 + t, N)];
    if (t == 0) lrow[256] = rowptr[min(n0 + 256, N)];
    #pragma unroll
    for (int k = 0; k < 4; ++k) lsum[t][k] = 0.f;
    __syncthreads();
    int cb = lrow[0];
    int cnt = gfill[b];
    int dmask = (1 << sb) - 1;
    for (int j = t; j < cnt; j += 256) {
        unsigned long long r = coarse[(size_t)cb + j];
        int s = (int)(r & dmask);
        int d = (int)((r >> sb) & dmask);
        unsigned e = (unsigned)(r >> (2 * sb));
        int local = d & ((1 << BSH) - 1);
        int pos = lrow[local] + atomicAdd(&lfill[local], 1);
        float4 ea = *(const float4*)&eattr[(size_t)e * 4];
        col[pos] = s;
        *(float4*)&eattr_perm[(size_t)pos * 4] = ea;
        atomicAdd(&lsum[local][0], ea.x);
        atomicAdd(&lsum[local][1], ea.y);
        atomicAdd(&lsum[local][2], ea.z);
        atomicAdd(&lsum[local][3], ea.w);
    }
    __syncthreads();
    int n = n0 + t;
    if (n < N) {
        int pos = lrow[t + 1] - 1;
        int dg = lrow[t + 1] - lrow[t] - 1;
        float inv = 1.f / fmaxf((float)dg, 1.f);
        col[pos] = n;
        *(float4*)&eattr_perm[(size_t)pos * 4] =
            make_float4(lsum[t][0] * inv, lsum[t][1] * inv, lsum[t][2] * inv, lsum[t][3] * inv);
    }
}

// W prep: Thi/Tlo[c][k] = bf16 hi/lo split of W[k][c], c in [0,256) = Wl|Wr.
__global__ __launch_bounds__(128) void wprep_kernel(
    const float* __restrict__ Wl, const float* __restrict__ Wr,
    unsigned short* __restrict__ Thi, unsigned short* __restrict__ Tlo)
{
    int c = blockIdx.x;
    int k = threadIdx.x;
    const float* W = (c < 128) ? Wl : Wr;
    float v = W[(size_t)k * 128 + (c & 127)];
    unsigned short h = bf16_rne(v);
    float lo = v - bf16_tof(h);
    Thi[(size_t)c * 128 + k] = h;
    Tlo[(size_t)c * 128 + k] = bf16_rne(lo);
}

// ---------------------------------------------------------------- MFMA GEMM, fp32 input (bf16x3)
__global__ __launch_bounds__(256, 4) void gemm_mfma_kernel(
    const float* __restrict__ H,
    const unsigned short* __restrict__ Thi, const unsigned short* __restrict__ Tlo,
    unsigned short* __restrict__ XLH, unsigned short* __restrict__ XRH, int nrows)
{
    __shared__ unsigned short sHi[32 * 128];
    __shared__ unsigned short sLo[32 * 128];
    int t = threadIdx.x;
    int r0 = blockIdx.x * 32;

    #pragma unroll
    for (int i = 0; i < 2; ++i) {
        int idx = t + i * 256;
        int row = idx >> 4, chunk = idx & 15;
        int gr = min(r0 + row, nrows - 1);
        float4 a = *(const float4*)&H[(size_t)gr * 128 + chunk * 8];
        float4 b = *(const float4*)&H[(size_t)gr * 128 + chunk * 8 + 4];
        float v[8] = {a.x, a.y, a.z, a.w, b.x, b.y, b.z, b.w};
        union { bf16x8 v; unsigned short u[8]; } hv, lv;
        #pragma unroll
        for (int j = 0; j < 8; ++j) {
            unsigned short h = bf16_rne(v[j]);
            hv.u[j] = h;
            lv.u[j] = bf16_rne(v[j] - bf16_tof(h));
        }
        int slot = chunk ^ (row & 7);
        *(bf16x8*)&sHi[row * 128 + slot * 8] = hv.v;
        *(bf16x8*)&sLo[row * 128 + slot * 8] = lv.v;
    }
    __syncthreads();

    int w  = t >> 6;
    int l  = t & 63;
    int lr = l & 15;
    int lk = l >> 4;
    int cbase = w * 64;

    f32x4 acc[2][4];
    #pragma unroll
    for (int i = 0; i < 2; ++i)
        #pragma unroll
        for (int j = 0; j < 4; ++j)
            acc[i][j] = (f32x4){0.f, 0.f, 0.f, 0.f};

    #pragma unroll
    for (int k0 = 0; k0 < 128; k0 += 32) {
        bf16x8 ah[2], al[2];
        #pragma unroll
        for (int rt = 0; rt < 2; ++rt) {
            int row = rt * 16 + lr;
            int chunk = (k0 >> 3) + lk;
            int slot = chunk ^ (row & 7);
            ah[rt] = *(const bf16x8*)&sHi[row * 128 + slot * 8];
            al[rt] = *(const bf16x8*)&sLo[row * 128 + slot * 8];
        }
        int k = k0 + lk * 8;
        #pragma unroll
        for (int ct = 0; ct < 4; ++ct) {
            int c = cbase + ct * 16 + lr;
            bf16x8 bh = *(const bf16x8*)&Thi[(size_t)c * 128 + k];
            bf16x8 bl = *(const bf16x8*)&Tlo[(size_t)c * 128 + k];
            #pragma unroll
            for (int rt = 0; rt < 2; ++rt) {
                acc[rt][ct] = __builtin_amdgcn_mfma_f32_16x16x32_bf16(ah[rt], bh, acc[rt][ct], 0, 0, 0);
                acc[rt][ct] = __builtin_amdgcn_mfma_f32_16x16x32_bf16(al[rt], bh, acc[rt][ct], 0, 0, 0);
                acc[rt][ct] = __builtin_amdgcn_mfma_f32_16x16x32_bf16(ah[rt], bl, acc[rt][ct], 0, 0, 0);
            }
        }
    }

    unsigned short* OUT = (w < 2) ? XLH : XRH;
    int ccol0 = (cbase & 127);
    #pragma unroll
    for (int rt = 0; rt < 2; ++rt)
        #pragma unroll
        for (int ct = 0; ct < 4; ++ct) {
            int cc = ccol0 + ct * 16 + lr;
            #pragma unroll
            for (int q = 0; q < 4; ++q) {
                int r = r0 + rt * 16 + lk * 4 + q;
                if (r < nrows) OUT[(size_t)r * 128 + cc] = bf16_rne(acc[rt][ct][q]);
            }
        }
}

// ---------------------------------------------------------------- MFMA GEMM, bf16 input
// H already bf16 => hi/lo split has lo==0: only 2 MFMAs (ah*bh + ah*bl),
// half the staging bytes and LDS of the fp32-input version.
__global__ __launch_bounds__(256, 4) void gemm_mfma_bf16_kernel(
    const unsigned short* __restrict__ H,
    const unsigned short* __restrict__ Thi, const unsigned short* __restrict__ Tlo,
    unsigned short* __restrict__ XLH, unsigned short* __restrict__ XRH, int nrows)
{
    __shared__ unsigned short sH[32 * 128];
    int t = threadIdx.x;
    int r0 = blockIdx.x * 32;

    #pragma unroll
    for (int i = 0; i < 2; ++i) {
        int idx = t + i * 256;
        int row = idx >> 4, chunk = idx & 15;
        int gr = min(r0 + row, nrows - 1);
        bf16x8 hv = *(const bf16x8*)&H[(size_t)gr * 128 + chunk * 8];
        int slot = chunk ^ (row & 7);
        *(bf16x8*)&sH[row * 128 + slot * 8] = hv;
    }
    __syncthreads();

    int w  = t >> 6;
    int l  = t & 63;
    int lr = l & 15;
    int lk = l >> 4;
    int cbase = w * 64;

    f32x4 acc[2][4];
    #pragma unroll
    for (int i = 0; i < 2; ++i)
        #pragma unroll
        for (int j = 0; j < 4; ++j)
            acc[i][j] = (f32x4){0.f, 0.f, 0.f, 0.f};

    #pragma unroll
    for (int k0 = 0; k0 < 128; k0 += 32) {
        bf16x8 ah[2];
        #pragma unroll
        for (int rt = 0; rt < 2; ++rt) {
            int row = rt * 16 + lr;
            int chunk = (k0 >> 3) + lk;
            int slot = chunk ^ (row & 7);
            ah[rt] = *(const bf16x8*)&sH[row * 128 + slot * 8];
        }
        int k = k0 + lk * 8;
        #pragma unroll
        for (int ct = 0; ct < 4; ++ct) {
            int c = cbase + ct * 16 + lr;
            bf16x8 bh = *(const bf16x8*)&Thi[(size_t)c * 128 + k];
            bf16x8 bl = *(const bf16x8*)&Tlo[(size_t)c * 128 + k];
            #pragma unroll
            for (int rt = 0; rt < 2; ++rt) {
                acc[rt][ct] = __builtin_amdgcn_mfma_f32_16x16x32_bf16(ah[rt], bh, acc[rt][ct], 0, 0, 0);
                acc[rt][ct] = __builtin_amdgcn_mfma_f32_16x16x32_bf16(ah[rt], bl, acc[rt][ct], 0, 0, 0);
            }
        }
    }

    unsigned short* OUT = (w < 2) ? XLH : XRH;
    int ccol0 = (cbase & 127);
    #pragma unroll
    for (int rt = 0; rt < 2; ++rt)
        #pragma unroll
        for (int ct = 0; ct < 4; ++ct) {
            int cc = ccol0 + ct * 16 + lr;
            #pragma unroll
            for (int q = 0; q < 4; ++q) {
                int r = r0 + rt * 16 + lk * 4 + q;
                if (r < nrows) OUT[(size_t)r * 128 + cc] = bf16_rne(acc[rt][ct][q]);
            }
        }
}

// ---------------------------------------------------------------- fused GATv2 attention + aggregation
// do_relu layers (0,1) write relu'd h as bf16 to outh; final layer writes fp32.
__global__ __launch_bounds__(256) void gat_agg_kernel(
    const unsigned short* __restrict__ xlh, const unsigned short* __restrict__ xrh,
    const int* __restrict__ rowptr, const int* __restrict__ col,
    const float* __restrict__ eattr_perm,
    const float* __restrict__ We, const float* __restrict__ att, const float* __restrict__ bias,
    unsigned short* __restrict__ outh, float* __restrict__ outf, int N, int do_relu)
{
    int w = threadIdx.x >> 6;
    int lane = threadIdx.x & 63;
    int g = lane >> 4;
    int lg = lane & 15;
    int c0 = lg * 8;

    f32x2 at2[4], we2[4][4];
    #pragma unroll
    for (int p = 0; p < 4; ++p) at2[p] = (f32x2){att[c0 + 2 * p], att[c0 + 2 * p + 1]};
    #pragma unroll
    for (int k = 0; k < 4; ++k)
        #pragma unroll
        for (int p = 0; p < 4; ++p)
            we2[k][p] = (f32x2){We[k * 128 + c0 + 2 * p], We[k * 128 + c0 + 2 * p + 1]};

    int nbase = (blockIdx.x * 4 + w) * 4;
    if (nbase >= N) return;

    int rptr[5];
    #pragma unroll
    for (int j = 0; j < 5; ++j) rptr[j] = rowptr[min(nbase + j, N)];

    #pragma unroll 1
    for (int i = 0; i < 4; ++i) {
        int n = nbase + i;
        int nc = min(n, N - 1);

        f32x2 xr2[4];
        {
            bfpack xrp;
            xrp.v = *(const bf16x8*)&xrh[((size_t)nc << 7) + c0];
            #pragma unroll
            for (int p = 0; p < 4; ++p) {
                unsigned int u = xrp.u[p];
                xr2[p] = (f32x2){__uint_as_float(u << 16), __uint_as_float(u & 0xffff0000u)};
            }
        }

        int e0 = rptr[i], e1 = rptr[i + 1];
        int elim = e1 - 1;
        int iters = (e1 - e0 + 3) >> 2;

        float m = -INFINITY, den = 0.f;
        f32x2 acc2[4];
        #pragma unroll
        for (int p = 0; p < 4; ++p) acc2[p] = (f32x2){0.f, 0.f};

        auto process = [&](const float4& ea, const bfpack& xv, bool valid) {
            f32x2 xl2[4];
            #pragma unroll
            for (int p = 0; p < 4; ++p) {
                unsigned int u = xv.u[p];
                xl2[p] = (f32x2){__uint_as_float(u << 16), __uint_as_float(u & 0xffff0000u)};
            }
            f32x2 vd = (f32x2){0.f, 0.f};
            #pragma unroll
            for (int p = 0; p < 4; ++p) {
                f32x2 z = xl2[p] + xr2[p];
                z += splat2(ea.x) * we2[0][p];
                z += splat2(ea.y) * we2[1][p];
                z += splat2(ea.z) * we2[2][p];
                z += splat2(ea.w) * we2[3][p];
                f32x2 zs = splat2(SLOPE) * z;
                f32x2 lz = (f32x2){fmaxf(z.x, zs.x), fmaxf(z.y, zs.y)};
                vd += lz * at2[p];
            }
            float v = dpp_red16(vd.x + vd.y);
            v = valid ? v : -INFINITY;
            bool trig = (v - m > 8.0f);
            if (__any(trig)) {
                float mnew  = fmaxf(m, v);
                float scale = __expf(m - mnew);
                float wgt   = __expf(v - mnew);
                den = den * scale + wgt;
                #pragma unroll
                for (int p = 0; p < 4; ++p)
                    acc2[p] = acc2[p] * splat2(scale) + splat2(wgt) * xl2[p];
                m = mnew;
            } else {
                float wgt = __expf(v - m);
                den += wgt;
                #pragma unroll
                for (int p = 0; p < 4; ++p) acc2[p] += splat2(wgt) * xl2[p];
            }
        };

        int e = e0 + g;
        int ec = min(e, elim);
        int cc = col[ec];
        int cA = col[min(e + 4, elim)];
        float4 eaA = *(const float4*)&eattr_perm[(size_t)ec * 4];
        bfpack xlA;
        xlA.v = *(const bf16x8*)&xlh[((size_t)(unsigned)cc << 7) + c0];
        float4 eaB;
        bfpack xlB;

        int it = 0;
        for (; it + 2 <= iters; it += 2) {
            int enc = min(e + 4, elim);
            eaB = *(const float4*)&eattr_perm[(size_t)enc * 4];
            xlB.v = *(const bf16x8*)&xlh[((size_t)(unsigned)cA << 7) + c0];
            cA = col[min(e + 8, elim)];
            process(eaA, xlA, e < e1);
            e += 4;

            enc = min(e + 4, elim);
            eaA = *(const float4*)&eattr_perm[(size_t)enc * 4];
            xlA.v = *(const bf16x8*)&xlh[((size_t)(unsigned)cA << 7) + c0];
            cA = col[min(e + 8, elim)];
            process(eaB, xlB, e < e1);
            e += 4;
        }
        if (it < iters) process(eaA, xlA, e < e1);

        float M = fmaxf(m, __shfl_xor(m, 16));
        M = fmaxf(M, __shfl_xor(M, 32));
        float sc = __expf(m - M);
        float d2 = den * sc;
        d2 += __shfl_xor(d2, 16);
        d2 += __shfl_xor(d2, 32);
        float inv = 1.f / (d2 + 1e-16f);
        float o[8];
        #pragma unroll
        for (int p = 0; p < 4; ++p) {
            float ax = acc2[p].x * sc;
            float ay = acc2[p].y * sc;
            ax += __shfl_xor(ax, 16); ax += __shfl_xor(ax, 32);
            ay += __shfl_xor(ay, 16); ay += __shfl_xor(ay, 32);
            o[2 * p] = ax * inv;
            o[2 * p + 1] = ay * inv;
        }
        if (n < N && g == 0) {
            if (do_relu) {
                union { bf16x8 v; unsigned short u[8]; } ov;
                #pragma unroll
                for (int j = 0; j < 8; ++j)
                    ov.u[j] = bf16_rne(fmaxf(o[j] + bias[c0 + j], 0.f));
                *(bf16x8*)&outh[((size_t)n << 7) + c0] = ov.v;
            } else {
                #pragma unroll
                for (int j = 0; j < 8; ++j) o[j] += bias[c0 + j];
                *(float4*)&outf[((size_t)n << 7) + c0]     = make_float4(o[0], o[1], o[2], o[3]);
                *(float4*)&outf[((size_t)n << 7) + c0 + 4] = make_float4(o[4], o[5], o[6], o[7]);
            }
        }
    }
}

// ---------------------------------------------------------------- launch

static inline char* carve(char*& p, size_t bytes) {
    char* r = p;
    p += (bytes + 255) & ~(size_t)255;
    return r;
}

extern "C" void kernel_launch(void* const* d_in, const int* in_sizes, int n_in,
                              void* d_out, int out_size, void* d_ws, size_t ws_size,
                              hipStream_t stream)
{
    const int* edge_index = (const int*)d_in[0];
    int E = in_sizes[0] / 2;
    int N = in_sizes[2] / 128;
    const int* srcv = edge_index;
    const int* dstv = edge_index + E;
    const float* eattr = (const float*)d_in[1];
    const float* x = (const float*)d_in[2];

    char* p = (char*)d_ws;
    int*   deg    = (int*)  carve(p, (size_t)N * 4);
    int*   gfill  = (int*)  carve(p, (size_t)512 * 4);
    int*   rowptr = (int*)  carve(p, (size_t)(N + 1) * 4);
    int*   bsum   = (int*)  carve(p, (size_t)1024 * 4);
    int*   col    = (int*)  carve(p, (size_t)(E + N) * 4);
    float* eperm  = (float*)carve(p, (size_t)(E + N) * 16);
    unsigned short* xlh = (unsigned short*)carve(p, (size_t)N * 256);
    unsigned short* xrh = (unsigned short*)carve(p, (size_t)N * 256);
    unsigned short* Thi = (unsigned short*)carve(p, (size_t)3 * 256 * 128 * 2);
    unsigned short* Tlo = (unsigned short*)carve(p, (size_t)3 * 256 * 128 * 2);
    // coarse record buffer aliases xlh (dead until first gemm)
    unsigned long long* coarse = (unsigned long long*)xlh;
    // interlayer bf16 h lives in d_out's storage (dead until final layer writes)
    unsigned short* hbuf = (unsigned short*)d_out;

    int sb = 1;
    while ((1 << sb) < N) ++sb;
    int nbuckets = (N + (1 << BSH) - 1) >> BSH;

    hipMemsetAsync(deg,   0, (size_t)N * 4,   stream);
    hipMemsetAsync(gfill, 0, (size_t)512 * 4, stream);

    int NB = (N + 1023) / 1024;
    int E4 = (E + 3) / 4;
    count_deg_kernel<<<(E4 + 255) / 256, 256, 0, stream>>>(dstv, deg, E);
    scanA_kernel<<<NB, 256, 0, stream>>>(deg, bsum, N);
    scanB_kernel<<<1, 1024, 0, stream>>>(bsum, NB);
    scanC_kernel<<<NB, 256, 0, stream>>>(deg, bsum, rowptr, N);
    bin_coarse_kernel<<<(E + CH - 1) / CH, 256, 0, stream>>>(
        srcv, dstv, rowptr, gfill, coarse, E, N, nbuckets, sb);
    bin_fine_kernel<<<nbuckets, 256, 0, stream>>>(
        coarse, gfill, rowptr, eattr, col, eperm, N, sb);

    for (int li = 0; li < 3; ++li) {
        const float* Wl = (const float*)d_in[3 + 5 * li + 0];
        const float* Wr = (const float*)d_in[3 + 5 * li + 1];
        wprep_kernel<<<256, 128, 0, stream>>>(Wl, Wr,
                                              Thi + (size_t)li * 256 * 128,
                                              Tlo + (size_t)li * 256 * 128);
    }

    float* out = (float*)d_out;
    for (int li = 0; li < 3; ++li) {
        const float* Wep = (const float*)d_in[3 + 5 * li + 2];
        const float* atp = (const float*)d_in[3 + 5 * li + 3];
        const float* bp  = (const float*)d_in[3 + 5 * li + 4];
        if (li == 0) {
            gemm_mfma_kernel<<<(N + 31) / 32, 256, 0, stream>>>(
                x, Thi + (size_t)li * 256 * 128, Tlo + (size_t)li * 256 * 128, xlh, xrh, N);
        } else {
            gemm_mfma_bf16_kernel<<<(N + 31) / 32, 256, 0, stream>>>(
                hbuf, Thi + (size_t)li * 256 * 128, Tlo + (size_t)li * 256 * 128, xlh, xrh, N);
        }
        gat_agg_kernel<<<(N + 15) / 16, 256, 0, stream>>>(xlh, xrh, rowptr, col, eperm,
                                                          Wep, atp, bp, hbuf, out, N,
                                                          li < 2 ? 1 : 0);
    }
}

// Round 15
// 589.324 us; speedup vs baseline: 1.2338x; 1.1239x over previous
//
#include <hip/hip_runtime.h>
#include <hip/hip_bf16.h>
#include <cmath>

#define SLOPE 0.2f
#define CH 8192
#define BSH 8

typedef __attribute__((ext_vector_type(8))) short bf16x8;
typedef __attribute__((ext_vector_type(4))) float f32x4;
typedef __attribute__((ext_vector_type(2))) float f32x2;

union bfpack { bf16x8 v; unsigned int u[4]; };

__device__ __forceinline__ unsigned short bf16_rne(float x) {
    unsigned int b = __float_as_uint(x);
    b += 0x7FFFu + ((b >> 16) & 1u);
    return (unsigned short)(b >> 16);
}
__device__ __forceinline__ float bf16_tof(unsigned short h) {
    return __uint_as_float(((unsigned int)h) << 16);
}
__device__ __forceinline__ f32x2 splat2(float s) { return (f32x2){s, s}; }

// sum over 16-lane groups entirely in the VALU via DPP (no ds_bpermute)
__device__ __forceinline__ float dpp_red16(float x) {
    int y;
    y = __builtin_amdgcn_update_dpp(0, __float_as_int(x), 0xB1, 0xF, 0xF, true);
    x += __int_as_float(y);
    y = __builtin_amdgcn_update_dpp(0, __float_as_int(x), 0x4E, 0xF, 0xF, true);
    x += __int_as_float(y);
    y = __builtin_amdgcn_update_dpp(0, __float_as_int(x), 0x141, 0xF, 0xF, true);
    x += __int_as_float(y);
    y = __builtin_amdgcn_update_dpp(0, __float_as_int(x), 0x140, 0xF, 0xF, true);
    x += __int_as_float(y);
    return x;
}

// ---------------------------------------------------------------- preprocessing
// bucket = dst >> BSH (391 buckets of 256 nodes). No per-node count_deg pass:
// rowptr is built inside bin_fine from LDS-counted degrees.

__global__ __launch_bounds__(256) void bucket_count_kernel(
    const int* __restrict__ dstv, int* __restrict__ gbc, int E)
{
    __shared__ int lc[512];
    int t = threadIdx.x;
    for (int i = t; i < 512; i += 256) lc[i] = 0;
    __syncthreads();
    int base = blockIdx.x * CH;
    int count = min(CH, E - base);
    for (int j = t; j < count; j += 256)
        atomicAdd(&lc[dstv[base + j] >> BSH], 1);
    __syncthreads();
    for (int i = t; i < 512; i += 256)
        if (lc[i]) atomicAdd(&gbc[i], lc[i]);
}

// exclusive scan of <=512 bucket counts, one block of 512 threads
__global__ void bucket_scan_kernel(const int* __restrict__ gbc, int* __restrict__ bptr, int nb)
{
    __shared__ int wsum[8];
    int t = threadIdx.x;
    int lane = t & 63, wv = t >> 6;
    int v = (t < nb) ? gbc[t] : 0;
    int incl = v;
    #pragma unroll
    for (int off = 1; off < 64; off <<= 1) {
        int u = __shfl_up(incl, off);
        if (lane >= off) incl += u;
    }
    if (lane == 63) wsum[wv] = incl;
    __syncthreads();
    int add = 0;
    for (int i = 0; i < wv; ++i) add += wsum[i];
    if (t < nb) bptr[t] = add + incl - v;
}

// coarse: bin CH edges/block by bucket in LDS, flush contiguous runs to
// globally-reserved ranges (mostly-full cachelines, coalesced).
__global__ __launch_bounds__(256, 2) void bin_coarse_kernel(
    const int* __restrict__ srcv, const int* __restrict__ dstv,
    const int* __restrict__ bptr, int* __restrict__ gfill,
    unsigned long long* __restrict__ coarse, int E, int nbuckets, int sb)
{
    __shared__ unsigned long long recs[CH];
    __shared__ int lcount[512];
    __shared__ int loffs[512];
    __shared__ int gpos[512];
    __shared__ int cbase[512];
    int t = threadIdx.x;
    int base = blockIdx.x * CH;
    int count = min(CH, E - base);

    for (int b = t; b < 512; b += 256) lcount[b] = 0;
    __syncthreads();

    int rank[CH / 256];
    #pragma unroll
    for (int i = 0; i < CH / 256; ++i) {
        int j = i * 256 + t;
        if (j < count) {
            int d = dstv[base + j];
            rank[i] = atomicAdd(&lcount[d >> BSH], 1);
        }
    }
    __syncthreads();

    loffs[t] = lcount[t];
    loffs[t + 256] = lcount[t + 256];
    __syncthreads();
    for (int off = 1; off < 512; off <<= 1) {
        int i0 = t, i1 = t + 256;
        int v0 = (i0 >= off) ? loffs[i0 - off] : 0;
        int v1 = (i1 >= off) ? loffs[i1 - off] : 0;
        __syncthreads();
        loffs[i0] += v0;
        loffs[i1] += v1;
        __syncthreads();
    }

    #pragma unroll
    for (int i = 0; i < CH / 256; ++i) {
        int j = i * 256 + t;
        if (j < count) {
            int e = base + j;
            int d = dstv[e];
            int s = srcv[e];
            int b = d >> BSH;
            int slot = loffs[b] - lcount[b] + rank[i];
            recs[slot] = (unsigned long long)(unsigned)s
                       | ((unsigned long long)(unsigned)d << sb)
                       | ((unsigned long long)(unsigned)e << (2 * sb));
        }
    }
    __syncthreads();
    for (int b = t; b < nbuckets; b += 256) {
        int c = lcount[b];
        gpos[b] = c ? atomicAdd(&gfill[b], c) : 0;
        cbase[b] = bptr[b];
    }
    __syncthreads();
    int dmask = (1 << sb) - 1;
    for (int j = t; j < count; j += 256) {
        unsigned long long r = recs[j];
        int d = (int)((r >> sb) & dmask);
        int b = d >> BSH;
        int excl = loffs[b] - lcount[b];
        __builtin_nontemporal_store(r, &coarse[(size_t)cbase[b] + gpos[b] + (j - excl)]);
    }
}

// fine: one block per bucket. Pass A counts per-node degrees (LDS) from the
// L2-hot coarse records; block scan builds and WRITES rowptr; pass B places
// col/eattr_perm and accumulates self-loop mean attrs. count_deg + 3 scan
// kernels eliminated.
__global__ __launch_bounds__(256) void bin_fine_kernel(
    const unsigned long long* __restrict__ coarse, const int* __restrict__ gbc,
    const int* __restrict__ bptr, const float* __restrict__ eattr,
    int* __restrict__ col, float* __restrict__ eattr_perm, int* __restrict__ rowptr,
    int N, int E, int nbuckets, int sb)
{
    __shared__ int ldeg[256];
    __shared__ int lrow[256];
    __shared__ int lfill[256];
    __shared__ float lsum[256][4];
    __shared__ int wpart[4];
    int b = blockIdx.x;
    int t = threadIdx.x;
    int n0 = b << BSH;
    ldeg[t] = 0;
    lfill[t] = 0;
    #pragma unroll
    for (int k = 0; k < 4; ++k) lsum[t][k] = 0.f;
    __syncthreads();
    int cb = bptr[b];
    int cnt = gbc[b];
    int dmask = (1 << sb) - 1;
    // pass A: per-node degree count
    for (int j = t; j < cnt; j += 256) {
        unsigned long long r = coarse[(size_t)cb + j];
        int d = (int)((r >> sb) & dmask);
        atomicAdd(&ldeg[d & ((1 << BSH) - 1)], 1);
    }
    __syncthreads();
    // block scan of (deg+1) -> rowptr for this bucket's nodes
    int nvalid = min(256, N - n0);
    int v = (t < nvalid) ? (ldeg[t] + 1) : 0;
    int lane = t & 63, wv = t >> 6;
    int incl = v;
    #pragma unroll
    for (int off = 1; off < 64; off <<= 1) {
        int u = __shfl_up(incl, off);
        if (lane >= off) incl += u;
    }
    if (lane == 63) wpart[wv] = incl;
    __syncthreads();
    int wadd = 0;
    for (int i = 0; i < wv; ++i) wadd += wpart[i];
    int myrow = cb + n0 + wadd + incl - v;   // rowptr[n0+t]
    lrow[t] = myrow;
    if (t < nvalid) rowptr[n0 + t] = myrow;
    if (b == nbuckets - 1 && t == 0) rowptr[N] = E + N;
    __syncthreads();
    // pass B: place records (coarse region is L2-hot from pass A)
    for (int j = t; j < cnt; j += 256) {
        unsigned long long r = coarse[(size_t)cb + j];
        int s = (int)(r & dmask);
        int d = (int)((r >> sb) & dmask);
        unsigned e = (unsigned)(r >> (2 * sb));
        int local = d & ((1 << BSH) - 1);
        int pos = lrow[local] + atomicAdd(&lfill[local], 1);
        float4 ea = *(const float4*)&eattr[(size_t)e * 4];
        col[pos] = s;
        *(float4*)&eattr_perm[(size_t)pos * 4] = ea;
        atomicAdd(&lsum[local][0], ea.x);
        atomicAdd(&lsum[local][1], ea.y);
        atomicAdd(&lsum[local][2], ea.z);
        atomicAdd(&lsum[local][3], ea.w);
    }
    __syncthreads();
    if (t < nvalid) {
        int dg = ldeg[t];
        int pos = lrow[t] + dg;
        float inv = 1.f / fmaxf((float)dg, 1.f);
        col[pos] = n0 + t;
        *(float4*)&eattr_perm[(size_t)pos * 4] =
            make_float4(lsum[t][0] * inv, lsum[t][1] * inv, lsum[t][2] * inv, lsum[t][3] * inv);
    }
}

// W prep: Thi/Tlo[c][k] = bf16 hi/lo split of W[k][c], c in [0,256) = Wl|Wr.
__global__ __launch_bounds__(128) void wprep_kernel(
    const float* __restrict__ Wl, const float* __restrict__ Wr,
    unsigned short* __restrict__ Thi, unsigned short* __restrict__ Tlo)
{
    int c = blockIdx.x;
    int k = threadIdx.x;
    const float* W = (c < 128) ? Wl : Wr;
    float v = W[(size_t)k * 128 + (c & 127)];
    unsigned short h = bf16_rne(v);
    float lo = v - bf16_tof(h);
    Thi[(size_t)c * 128 + k] = h;
    Tlo[(size_t)c * 128 + k] = bf16_rne(lo);
}

// ---------------------------------------------------------------- MFMA GEMM, fp32 input (bf16x3)
__global__ __launch_bounds__(256, 4) void gemm_mfma_kernel(
    const float* __restrict__ H,
    const unsigned short* __restrict__ Thi, const unsigned short* __restrict__ Tlo,
    unsigned short* __restrict__ XLH, unsigned short* __restrict__ XRH, int nrows)
{
    __shared__ unsigned short sHi[32 * 128];
    __shared__ unsigned short sLo[32 * 128];
    int t = threadIdx.x;
    int r0 = blockIdx.x * 32;

    #pragma unroll
    for (int i = 0; i < 2; ++i) {
        int idx = t + i * 256;
        int row = idx >> 4, chunk = idx & 15;
        int gr = min(r0 + row, nrows - 1);
        float4 a = *(const float4*)&H[(size_t)gr * 128 + chunk * 8];
        float4 b = *(const float4*)&H[(size_t)gr * 128 + chunk * 8 + 4];
        float v[8] = {a.x, a.y, a.z, a.w, b.x, b.y, b.z, b.w};
        union { bf16x8 v; unsigned short u[8]; } hv, lv;
        #pragma unroll
        for (int j = 0; j < 8; ++j) {
            unsigned short h = bf16_rne(v[j]);
            hv.u[j] = h;
            lv.u[j] = bf16_rne(v[j] - bf16_tof(h));
        }
        int slot = chunk ^ (row & 7);
        *(bf16x8*)&sHi[row * 128 + slot * 8] = hv.v;
        *(bf16x8*)&sLo[row * 128 + slot * 8] = lv.v;
    }
    __syncthreads();

    int w  = t >> 6;
    int l  = t & 63;
    int lr = l & 15;
    int lk = l >> 4;
    int cbase = w * 64;

    f32x4 acc[2][4];
    #pragma unroll
    for (int i = 0; i < 2; ++i)
        #pragma unroll
        for (int j = 0; j < 4; ++j)
            acc[i][j] = (f32x4){0.f, 0.f, 0.f, 0.f};

    #pragma unroll
    for (int k0 = 0; k0 < 128; k0 += 32) {
        bf16x8 ah[2], al[2];
        #pragma unroll
        for (int rt = 0; rt < 2; ++rt) {
            int row = rt * 16 + lr;
            int chunk = (k0 >> 3) + lk;
            int slot = chunk ^ (row & 7);
            ah[rt] = *(const bf16x8*)&sHi[row * 128 + slot * 8];
            al[rt] = *(const bf16x8*)&sLo[row * 128 + slot * 8];
        }
        int k = k0 + lk * 8;
        #pragma unroll
        for (int ct = 0; ct < 4; ++ct) {
            int c = cbase + ct * 16 + lr;
            bf16x8 bh = *(const bf16x8*)&Thi[(size_t)c * 128 + k];
            bf16x8 bl = *(const bf16x8*)&Tlo[(size_t)c * 128 + k];
            #pragma unroll
            for (int rt = 0; rt < 2; ++rt) {
                acc[rt][ct] = __builtin_amdgcn_mfma_f32_16x16x32_bf16(ah[rt], bh, acc[rt][ct], 0, 0, 0);
                acc[rt][ct] = __builtin_amdgcn_mfma_f32_16x16x32_bf16(al[rt], bh, acc[rt][ct], 0, 0, 0);
                acc[rt][ct] = __builtin_amdgcn_mfma_f32_16x16x32_bf16(ah[rt], bl, acc[rt][ct], 0, 0, 0);
            }
        }
    }

    unsigned short* OUT = (w < 2) ? XLH : XRH;
    int ccol0 = (cbase & 127);
    #pragma unroll
    for (int rt = 0; rt < 2; ++rt)
        #pragma unroll
        for (int ct = 0; ct < 4; ++ct) {
            int cc = ccol0 + ct * 16 + lr;
            #pragma unroll
            for (int q = 0; q < 4; ++q) {
                int r = r0 + rt * 16 + lk * 4 + q;
                if (r < nrows) OUT[(size_t)r * 128 + cc] = bf16_rne(acc[rt][ct][q]);
            }
        }
}

// ---------------------------------------------------------------- MFMA GEMM, bf16 input (2 MFMAs)
__global__ __launch_bounds__(256, 4) void gemm_mfma_bf16_kernel(
    const unsigned short* __restrict__ H,
    const unsigned short* __restrict__ Thi, const unsigned short* __restrict__ Tlo,
    unsigned short* __restrict__ XLH, unsigned short* __restrict__ XRH, int nrows)
{
    __shared__ unsigned short sH[32 * 128];
    int t = threadIdx.x;
    int r0 = blockIdx.x * 32;

    #pragma unroll
    for (int i = 0; i < 2; ++i) {
        int idx = t + i * 256;
        int row = idx >> 4, chunk = idx & 15;
        int gr = min(r0 + row, nrows - 1);
        bf16x8 hv = *(const bf16x8*)&H[(size_t)gr * 128 + chunk * 8];
        int slot = chunk ^ (row & 7);
        *(bf16x8*)&sH[row * 128 + slot * 8] = hv;
    }
    __syncthreads();

    int w  = t >> 6;
    int l  = t & 63;
    int lr = l & 15;
    int lk = l >> 4;
    int cbase = w * 64;

    f32x4 acc[2][4];
    #pragma unroll
    for (int i = 0; i < 2; ++i)
        #pragma unroll
        for (int j = 0; j < 4; ++j)
            acc[i][j] = (f32x4){0.f, 0.f, 0.f, 0.f};

    #pragma unroll
    for (int k0 = 0; k0 < 128; k0 += 32) {
        bf16x8 ah[2];
        #pragma unroll
        for (int rt = 0; rt < 2; ++rt) {
            int row = rt * 16 + lr;
            int chunk = (k0 >> 3) + lk;
            int slot = chunk ^ (row & 7);
            ah[rt] = *(const bf16x8*)&sH[row * 128 + slot * 8];
        }
        int k = k0 + lk * 8;
        #pragma unroll
        for (int ct = 0; ct < 4; ++ct) {
            int c = cbase + ct * 16 + lr;
            bf16x8 bh = *(const bf16x8*)&Thi[(size_t)c * 128 + k];
            bf16x8 bl = *(const bf16x8*)&Tlo[(size_t)c * 128 + k];
            #pragma unroll
            for (int rt = 0; rt < 2; ++rt) {
                acc[rt][ct] = __builtin_amdgcn_mfma_f32_16x16x32_bf16(ah[rt], bh, acc[rt][ct], 0, 0, 0);
                acc[rt][ct] = __builtin_amdgcn_mfma_f32_16x16x32_bf16(ah[rt], bl, acc[rt][ct], 0, 0, 0);
            }
        }
    }

    unsigned short* OUT = (w < 2) ? XLH : XRH;
    int ccol0 = (cbase & 127);
    #pragma unroll
    for (int rt = 0; rt < 2; ++rt)
        #pragma unroll
        for (int ct = 0; ct < 4; ++ct) {
            int cc = ccol0 + ct * 16 + lr;
            #pragma unroll
            for (int q = 0; q < 4; ++q) {
                int r = r0 + rt * 16 + lk * 4 + q;
                if (r < nrows) OUT[(size_t)r * 128 + cc] = bf16_rne(acc[rt][ct][q]);
            }
        }
}

// ---------------------------------------------------------------- fused GATv2 attention + aggregation
__global__ __launch_bounds__(256) void gat_agg_kernel(
    const unsigned short* __restrict__ xlh, const unsigned short* __restrict__ xrh,
    const int* __restrict__ rowptr, const int* __restrict__ col,
    const float* __restrict__ eattr_perm,
    const float* __restrict__ We, const float* __restrict__ att, const float* __restrict__ bias,
    unsigned short* __restrict__ outh, float* __restrict__ outf, int N, int do_relu)
{
    int w = threadIdx.x >> 6;
    int lane = threadIdx.x & 63;
    int g = lane >> 4;
    int lg = lane & 15;
    int c0 = lg * 8;

    f32x2 at2[4], we2[4][4];
    #pragma unroll
    for (int p = 0; p < 4; ++p) at2[p] = (f32x2){att[c0 + 2 * p], att[c0 + 2 * p + 1]};
    #pragma unroll
    for (int k = 0; k < 4; ++k)
        #pragma unroll
        for (int p = 0; p < 4; ++p)
            we2[k][p] = (f32x2){We[k * 128 + c0 + 2 * p], We[k * 128 + c0 + 2 * p + 1]};

    int nbase = (blockIdx.x * 4 + w) * 4;
    if (nbase >= N) return;

    int rptr[5];
    #pragma unroll
    for (int j = 0; j < 5; ++j) rptr[j] = rowptr[min(nbase + j, N)];

    #pragma unroll 1
    for (int i = 0; i < 4; ++i) {
        int n = nbase + i;
        int nc = min(n, N - 1);

        f32x2 xr2[4];
        {
            bfpack xrp;
            xrp.v = *(const bf16x8*)&xrh[((size_t)nc << 7) + c0];
            #pragma unroll
            for (int p = 0; p < 4; ++p) {
                unsigned int u = xrp.u[p];
                xr2[p] = (f32x2){__uint_as_float(u << 16), __uint_as_float(u & 0xffff0000u)};
            }
        }

        int e0 = rptr[i], e1 = rptr[i + 1];
        int elim = e1 - 1;
        int iters = (e1 - e0 + 3) >> 2;

        float m = -INFINITY, den = 0.f;
        f32x2 acc2[4];
        #pragma unroll
        for (int p = 0; p < 4; ++p) acc2[p] = (f32x2){0.f, 0.f};

        auto process = [&](const float4& ea, const bfpack& xv, bool valid) {
            f32x2 xl2[4];
            #pragma unroll
            for (int p = 0; p < 4; ++p) {
                unsigned int u = xv.u[p];
                xl2[p] = (f32x2){__uint_as_float(u << 16), __uint_as_float(u & 0xffff0000u)};
            }
            f32x2 vd = (f32x2){0.f, 0.f};
            #pragma unroll
            for (int p = 0; p < 4; ++p) {
                f32x2 z = xl2[p] + xr2[p];
                z += splat2(ea.x) * we2[0][p];
                z += splat2(ea.y) * we2[1][p];
                z += splat2(ea.z) * we2[2][p];
                z += splat2(ea.w) * we2[3][p];
                f32x2 zs = splat2(SLOPE) * z;
                f32x2 lz = (f32x2){fmaxf(z.x, zs.x), fmaxf(z.y, zs.y)};
                vd += lz * at2[p];
            }
            float v = dpp_red16(vd.x + vd.y);
            v = valid ? v : -INFINITY;
            bool trig = (v - m > 8.0f);
            if (__any(trig)) {
                float mnew  = fmaxf(m, v);
                float scale = __expf(m - mnew);
                float wgt   = __expf(v - mnew);
                den = den * scale + wgt;
                #pragma unroll
                for (int p = 0; p < 4; ++p)
                    acc2[p] = acc2[p] * splat2(scale) + splat2(wgt) * xl2[p];
                m = mnew;
            } else {
                float wgt = __expf(v - m);
                den += wgt;
                #pragma unroll
                for (int p = 0; p < 4; ++p) acc2[p] += splat2(wgt) * xl2[p];
            }
        };

        int e = e0 + g;
        int ec = min(e, elim);
        int cc = col[ec];
        int cA = col[min(e + 4, elim)];
        float4 eaA = *(const float4*)&eattr_perm[(size_t)ec * 4];
        bfpack xlA;
        xlA.v = *(const bf16x8*)&xlh[((size_t)(unsigned)cc << 7) + c0];
        float4 eaB;
        bfpack xlB;

        int it = 0;
        for (; it + 2 <= iters; it += 2) {
            int enc = min(e + 4, elim);
            eaB = *(const float4*)&eattr_perm[(size_t)enc * 4];
            xlB.v = *(const bf16x8*)&xlh[((size_t)(unsigned)cA << 7) + c0];
            cA = col[min(e + 8, elim)];
            process(eaA, xlA, e < e1);
            e += 4;

            enc = min(e + 4, elim);
            eaA = *(const float4*)&eattr_perm[(size_t)enc * 4];
            xlA.v = *(const bf16x8*)&xlh[((size_t)(unsigned)cA << 7) + c0];
            cA = col[min(e + 8, elim)];
            process(eaB, xlB, e < e1);
            e += 4;
        }
        if (it < iters) process(eaA, xlA, e < e1);

        float M = fmaxf(m, __shfl_xor(m, 16));
        M = fmaxf(M, __shfl_xor(M, 32));
        float sc = __expf(m - M);
        float d2 = den * sc;
        d2 += __shfl_xor(d2, 16);
        d2 += __shfl_xor(d2, 32);
        float inv = 1.f / (d2 + 1e-16f);
        float o[8];
        #pragma unroll
        for (int p = 0; p < 4; ++p) {
            float ax = acc2[p].x * sc;
            float ay = acc2[p].y * sc;
            ax += __shfl_xor(ax, 16); ax += __shfl_xor(ax, 32);
            ay += __shfl_xor(ay, 16); ay += __shfl_xor(ay, 32);
            o[2 * p] = ax * inv;
            o[2 * p + 1] = ay * inv;
        }
        if (n < N && g == 0) {
            if (do_relu) {
                union { bf16x8 v; unsigned short u[8]; } ov;
                #pragma unroll
                for (int j = 0; j < 8; ++j)
                    ov.u[j] = bf16_rne(fmaxf(o[j] + bias[c0 + j], 0.f));
                *(bf16x8*)&outh[((size_t)n << 7) + c0] = ov.v;
            } else {
                #pragma unroll
                for (int j = 0; j < 8; ++j) o[j] += bias[c0 + j];
                *(float4*)&outf[((size_t)n << 7) + c0]     = make_float4(o[0], o[1], o[2], o[3]);
                *(float4*)&outf[((size_t)n << 7) + c0 + 4] = make_float4(o[4], o[5], o[6], o[7]);
            }
        }
    }
}

// ---------------------------------------------------------------- launch

static inline char* carve(char*& p, size_t bytes) {
    char* r = p;
    p += (bytes + 255) & ~(size_t)255;
    return r;
}

extern "C" void kernel_launch(void* const* d_in, const int* in_sizes, int n_in,
                              void* d_out, int out_size, void* d_ws, size_t ws_size,
                              hipStream_t stream)
{
    const int* edge_index = (const int*)d_in[0];
    int E = in_sizes[0] / 2;
    int N = in_sizes[2] / 128;
    const int* srcv = edge_index;
    const int* dstv = edge_index + E;
    const float* eattr = (const float*)d_in[1];
    const float* x = (const float*)d_in[2];

    char* p = (char*)d_ws;
    int*   gfill  = (int*)  carve(p, (size_t)512 * 4);
    int*   gbc    = (int*)  carve(p, (size_t)512 * 4);
    int*   bptr   = (int*)  carve(p, (size_t)512 * 4);
    int*   rowptr = (int*)  carve(p, (size_t)(N + 1) * 4);
    int*   col    = (int*)  carve(p, (size_t)(E + N) * 4);
    float* eperm  = (float*)carve(p, (size_t)(E + N) * 16);
    unsigned short* xlh = (unsigned short*)carve(p, (size_t)N * 256);
    unsigned short* xrh = (unsigned short*)carve(p, (size_t)N * 256);
    unsigned short* Thi = (unsigned short*)carve(p, (size_t)3 * 256 * 128 * 2);
    unsigned short* Tlo = (unsigned short*)carve(p, (size_t)3 * 256 * 128 * 2);
    // coarse record buffer aliases xlh (dead until first gemm; E*8 <= N*256)
    unsigned long long* coarse = (unsigned long long*)xlh;
    // interlayer bf16 h lives in d_out's storage (dead until final layer writes)
    unsigned short* hbuf = (unsigned short*)d_out;

    int sb = 1;
    while ((1 << sb) < N) ++sb;
    int nbuckets = (N + (1 << BSH) - 1) >> BSH;

    hipMemsetAsync(gfill, 0, (size_t)1024 * 4, stream);   // gfill + gbc (contiguous)

    bucket_count_kernel<<<(E + CH - 1) / CH, 256, 0, stream>>>(dstv, gbc, E);
    bucket_scan_kernel<<<1, 512, 0, stream>>>(gbc, bptr, nbuckets);
    bin_coarse_kernel<<<(E + CH - 1) / CH, 256, 0, stream>>>(
        srcv, dstv, bptr, gfill, coarse, E, nbuckets, sb);
    bin_fine_kernel<<<nbuckets, 256, 0, stream>>>(
        coarse, gbc, bptr, eattr, col, eperm, rowptr, N, E, nbuckets, sb);

    for (int li = 0; li < 3; ++li) {
        const float* Wl = (const float*)d_in[3 + 5 * li + 0];
        const float* Wr = (const float*)d_in[3 + 5 * li + 1];
        wprep_kernel<<<256, 128, 0, stream>>>(Wl, Wr,
                                              Thi + (size_t)li * 256 * 128,
                                              Tlo + (size_t)li * 256 * 128);
    }

    float* out = (float*)d_out;
    for (int li = 0; li < 3; ++li) {
        const float* Wep = (const float*)d_in[3 + 5 * li + 2];
        const float* atp = (const float*)d_in[3 + 5 * li + 3];
        const float* bp  = (const float*)d_in[3 + 5 * li + 4];
        if (li == 0) {
            gemm_mfma_kernel<<<(N + 31) / 32, 256, 0, stream>>>(
                x, Thi + (size_t)li * 256 * 128, Tlo + (size_t)li * 256 * 128, xlh, xrh, N);
        } else {
            gemm_mfma_bf16_kernel<<<(N + 31) / 32, 256, 0, stream>>>(
                hbuf, Thi + (size_t)li * 256 * 128, Tlo + (size_t)li * 256 * 128, xlh, xrh, N);
        }
        gat_agg_kernel<<<(N + 15) / 16, 256, 0, stream>>>(xlh, xrh, rowptr, col, eperm,
                                                          Wep, atp, bp, hbuf, out, N,
                                                          li < 2 ? 1 : 0);
    }
}

// Round 16
// 517.887 us; speedup vs baseline: 1.4040x; 1.1379x over previous
//
#include <hip/hip_runtime.h>
#include <hip/hip_bf16.h>
#include <cmath>

#define SLOPE 0.2f
#define CH 8192
#define BSH 8

typedef __attribute__((ext_vector_type(8))) short bf16x8;
typedef __attribute__((ext_vector_type(4))) float f32x4;
typedef __attribute__((ext_vector_type(2))) float f32x2;

union bfpack { bf16x8 v; unsigned int u[4]; };

__device__ __forceinline__ unsigned short bf16_rne(float x) {
    unsigned int b = __float_as_uint(x);
    b += 0x7FFFu + ((b >> 16) & 1u);
    return (unsigned short)(b >> 16);
}
__device__ __forceinline__ float bf16_tof(unsigned short h) {
    return __uint_as_float(((unsigned int)h) << 16);
}
__device__ __forceinline__ f32x2 splat2(float s) { return (f32x2){s, s}; }

// sum over 16-lane groups entirely in the VALU via DPP (no ds_bpermute)
__device__ __forceinline__ float dpp_red16(float x) {
    int y;
    y = __builtin_amdgcn_update_dpp(0, __float_as_int(x), 0xB1, 0xF, 0xF, true);
    x += __int_as_float(y);
    y = __builtin_amdgcn_update_dpp(0, __float_as_int(x), 0x4E, 0xF, 0xF, true);
    x += __int_as_float(y);
    y = __builtin_amdgcn_update_dpp(0, __float_as_int(x), 0x141, 0xF, 0xF, true);
    x += __int_as_float(y);
    y = __builtin_amdgcn_update_dpp(0, __float_as_int(x), 0x140, 0xF, 0xF, true);
    x += __int_as_float(y);
    return x;
}

// ---------------------------------------------------------------- preprocessing
// bucket = dst >> BSH (391 buckets of 256 nodes). rowptr built in bin_fine.

__global__ __launch_bounds__(256) void bucket_count_kernel(
    const int* __restrict__ dstv, int* __restrict__ gbc, int E)
{
    __shared__ int lc[512];
    int t = threadIdx.x;
    for (int i = t; i < 512; i += 256) lc[i] = 0;
    __syncthreads();
    int base = blockIdx.x * CH;
    int count = min(CH, E - base);
    for (int j = t; j < count; j += 256)
        atomicAdd(&lc[dstv[base + j] >> BSH], 1);
    __syncthreads();
    for (int i = t; i < 512; i += 256)
        if (lc[i]) atomicAdd(&gbc[i], lc[i]);
}

__global__ void bucket_scan_kernel(const int* __restrict__ gbc, int* __restrict__ bptr, int nb)
{
    __shared__ int wsum[8];
    int t = threadIdx.x;
    int lane = t & 63, wv = t >> 6;
    int v = (t < nb) ? gbc[t] : 0;
    int incl = v;
    #pragma unroll
    for (int off = 1; off < 64; off <<= 1) {
        int u = __shfl_up(incl, off);
        if (lane >= off) incl += u;
    }
    if (lane == 63) wsum[wv] = incl;
    __syncthreads();
    int add = 0;
    for (int i = 0; i < wv; ++i) add += wsum[i];
    if (t < nb) bptr[t] = add + incl - v;
}

__global__ __launch_bounds__(256, 2) void bin_coarse_kernel(
    const int* __restrict__ srcv, const int* __restrict__ dstv,
    const int* __restrict__ bptr, int* __restrict__ gfill,
    unsigned long long* __restrict__ coarse, int E, int nbuckets, int sb)
{
    __shared__ unsigned long long recs[CH];
    __shared__ int lcount[512];
    __shared__ int loffs[512];
    __shared__ int gpos[512];
    __shared__ int cbase[512];
    int t = threadIdx.x;
    int base = blockIdx.x * CH;
    int count = min(CH, E - base);

    for (int b = t; b < 512; b += 256) lcount[b] = 0;
    __syncthreads();

    int rank[CH / 256];
    #pragma unroll
    for (int i = 0; i < CH / 256; ++i) {
        int j = i * 256 + t;
        if (j < count) {
            int d = dstv[base + j];
            rank[i] = atomicAdd(&lcount[d >> BSH], 1);
        }
    }
    __syncthreads();

    loffs[t] = lcount[t];
    loffs[t + 256] = lcount[t + 256];
    __syncthreads();
    for (int off = 1; off < 512; off <<= 1) {
        int i0 = t, i1 = t + 256;
        int v0 = (i0 >= off) ? loffs[i0 - off] : 0;
        int v1 = (i1 >= off) ? loffs[i1 - off] : 0;
        __syncthreads();
        loffs[i0] += v0;
        loffs[i1] += v1;
        __syncthreads();
    }

    #pragma unroll
    for (int i = 0; i < CH / 256; ++i) {
        int j = i * 256 + t;
        if (j < count) {
            int e = base + j;
            int d = dstv[e];
            int s = srcv[e];
            int b = d >> BSH;
            int slot = loffs[b] - lcount[b] + rank[i];
            recs[slot] = (unsigned long long)(unsigned)s
                       | ((unsigned long long)(unsigned)d << sb)
                       | ((unsigned long long)(unsigned)e << (2 * sb));
        }
    }
    __syncthreads();
    for (int b = t; b < nbuckets; b += 256) {
        int c = lcount[b];
        gpos[b] = c ? atomicAdd(&gfill[b], c) : 0;
        cbase[b] = bptr[b];
    }
    __syncthreads();
    int dmask = (1 << sb) - 1;
    for (int j = t; j < count; j += 256) {
        unsigned long long r = recs[j];
        int d = (int)((r >> sb) & dmask);
        int b = d >> BSH;
        int excl = loffs[b] - lcount[b];
        __builtin_nontemporal_store(r, &coarse[(size_t)cbase[b] + gpos[b] + (j - excl)]);
    }
}

__global__ __launch_bounds__(256) void bin_fine_kernel(
    const unsigned long long* __restrict__ coarse, const int* __restrict__ gbc,
    const int* __restrict__ bptr, const float* __restrict__ eattr,
    int* __restrict__ col, float* __restrict__ eattr_perm, int* __restrict__ rowptr,
    int N, int E, int nbuckets, int sb)
{
    __shared__ int ldeg[256];
    __shared__ int lrow[256];
    __shared__ int lfill[256];
    __shared__ float lsum[256][4];
    __shared__ int wpart[4];
    int b = blockIdx.x;
    int t = threadIdx.x;
    int n0 = b << BSH;
    ldeg[t] = 0;
    lfill[t] = 0;
    #pragma unroll
    for (int k = 0; k < 4; ++k) lsum[t][k] = 0.f;
    __syncthreads();
    int cb = bptr[b];
    int cnt = gbc[b];
    int dmask = (1 << sb) - 1;
    for (int j = t; j < cnt; j += 256) {
        unsigned long long r = coarse[(size_t)cb + j];
        int d = (int)((r >> sb) & dmask);
        atomicAdd(&ldeg[d & ((1 << BSH) - 1)], 1);
    }
    __syncthreads();
    int nvalid = min(256, N - n0);
    int v = (t < nvalid) ? (ldeg[t] + 1) : 0;
    int lane = t & 63, wv = t >> 6;
    int incl = v;
    #pragma unroll
    for (int off = 1; off < 64; off <<= 1) {
        int u = __shfl_up(incl, off);
        if (lane >= off) incl += u;
    }
    if (lane == 63) wpart[wv] = incl;
    __syncthreads();
    int wadd = 0;
    for (int i = 0; i < wv; ++i) wadd += wpart[i];
    int myrow = cb + n0 + wadd + incl - v;
    lrow[t] = myrow;
    if (t < nvalid) rowptr[n0 + t] = myrow;
    if (b == nbuckets - 1 && t == 0) rowptr[N] = E + N;
    __syncthreads();
    for (int j = t; j < cnt; j += 256) {
        unsigned long long r = coarse[(size_t)cb + j];
        int s = (int)(r & dmask);
        int d = (int)((r >> sb) & dmask);
        unsigned e = (unsigned)(r >> (2 * sb));
        int local = d & ((1 << BSH) - 1);
        int pos = lrow[local] + atomicAdd(&lfill[local], 1);
        float4 ea = *(const float4*)&eattr[(size_t)e * 4];
        col[pos] = s;
        *(float4*)&eattr_perm[(size_t)pos * 4] = ea;
        atomicAdd(&lsum[local][0], ea.x);
        atomicAdd(&lsum[local][1], ea.y);
        atomicAdd(&lsum[local][2], ea.z);
        atomicAdd(&lsum[local][3], ea.w);
    }
    __syncthreads();
    if (t < nvalid) {
        int dg = ldeg[t];
        int pos = lrow[t] + dg;
        float inv = 1.f / fmaxf((float)dg, 1.f);
        col[pos] = n0 + t;
        *(float4*)&eattr_perm[(size_t)pos * 4] =
            make_float4(lsum[t][0] * inv, lsum[t][1] * inv, lsum[t][2] * inv, lsum[t][3] * inv);
    }
}

// W prep: element (k,c) of [Wl|Wr] stored at T[((k>>3)*256 + c)*8 + (k&7)]
// (k-chunk-major) so the gemm B-fragment load is 16-lane contiguous (256 B runs)
// instead of 64 scattered 128B lines.
__global__ __launch_bounds__(128) void wprep_kernel(
    const float* __restrict__ Wl, const float* __restrict__ Wr,
    unsigned short* __restrict__ Thi, unsigned short* __restrict__ Tlo)
{
    int c = blockIdx.x;
    int k = threadIdx.x;
    const float* W = (c < 128) ? Wl : Wr;
    float v = W[(size_t)k * 128 + (c & 127)];
    unsigned short h = bf16_rne(v);
    float lo = v - bf16_tof(h);
    size_t idx = ((size_t)(k >> 3) * 256 + c) * 8 + (k & 7);
    Thi[idx] = h;
    Tlo[idx] = bf16_rne(lo);
}

// ---------------------------------------------------------------- MFMA GEMM, fp32 input (bf16x3)
__global__ __launch_bounds__(256, 4) void gemm_mfma_kernel(
    const float* __restrict__ H,
    const unsigned short* __restrict__ Thi, const unsigned short* __restrict__ Tlo,
    unsigned short* __restrict__ XLH, unsigned short* __restrict__ XRH, int nrows)
{
    __shared__ unsigned short sHi[32 * 128];
    __shared__ unsigned short sLo[32 * 128];
    int t = threadIdx.x;
    int r0 = blockIdx.x * 32;

    #pragma unroll
    for (int i = 0; i < 2; ++i) {
        int idx = t + i * 256;
        int row = idx >> 4, chunk = idx & 15;
        int gr = min(r0 + row, nrows - 1);
        float4 a = *(const float4*)&H[(size_t)gr * 128 + chunk * 8];
        float4 b = *(const float4*)&H[(size_t)gr * 128 + chunk * 8 + 4];
        float v[8] = {a.x, a.y, a.z, a.w, b.x, b.y, b.z, b.w};
        union { bf16x8 v; unsigned short u[8]; } hv, lv;
        #pragma unroll
        for (int j = 0; j < 8; ++j) {
            unsigned short h = bf16_rne(v[j]);
            hv.u[j] = h;
            lv.u[j] = bf16_rne(v[j] - bf16_tof(h));
        }
        int slot = chunk ^ (row & 7);
        *(bf16x8*)&sHi[row * 128 + slot * 8] = hv.v;
        *(bf16x8*)&sLo[row * 128 + slot * 8] = lv.v;
    }
    __syncthreads();

    int w  = t >> 6;
    int l  = t & 63;
    int lr = l & 15;
    int lk = l >> 4;
    int cbase = w * 64;

    f32x4 acc[2][4];
    #pragma unroll
    for (int i = 0; i < 2; ++i)
        #pragma unroll
        for (int j = 0; j < 4; ++j)
            acc[i][j] = (f32x4){0.f, 0.f, 0.f, 0.f};

    #pragma unroll
    for (int k0 = 0; k0 < 128; k0 += 32) {
        bf16x8 ah[2], al[2];
        #pragma unroll
        for (int rt = 0; rt < 2; ++rt) {
            int row = rt * 16 + lr;
            int chunk = (k0 >> 3) + lk;
            int slot = chunk ^ (row & 7);
            ah[rt] = *(const bf16x8*)&sHi[row * 128 + slot * 8];
            al[rt] = *(const bf16x8*)&sLo[row * 128 + slot * 8];
        }
        int kc = (k0 >> 3) + lk;
        #pragma unroll
        for (int ct = 0; ct < 4; ++ct) {
            int c = cbase + ct * 16 + lr;
            size_t bidx = ((size_t)kc * 256 + c) * 8;
            bf16x8 bh = *(const bf16x8*)&Thi[bidx];
            bf16x8 bl = *(const bf16x8*)&Tlo[bidx];
            #pragma unroll
            for (int rt = 0; rt < 2; ++rt) {
                acc[rt][ct] = __builtin_amdgcn_mfma_f32_16x16x32_bf16(ah[rt], bh, acc[rt][ct], 0, 0, 0);
                acc[rt][ct] = __builtin_amdgcn_mfma_f32_16x16x32_bf16(al[rt], bh, acc[rt][ct], 0, 0, 0);
                acc[rt][ct] = __builtin_amdgcn_mfma_f32_16x16x32_bf16(ah[rt], bl, acc[rt][ct], 0, 0, 0);
            }
        }
    }

    unsigned short* OUT = (w < 2) ? XLH : XRH;
    int ccol0 = (cbase & 127);
    #pragma unroll
    for (int rt = 0; rt < 2; ++rt)
        #pragma unroll
        for (int ct = 0; ct < 4; ++ct) {
            int cc = ccol0 + ct * 16 + lr;
            #pragma unroll
            for (int q = 0; q < 4; ++q) {
                int r = r0 + rt * 16 + lk * 4 + q;
                if (r < nrows) OUT[(size_t)r * 128 + cc] = bf16_rne(acc[rt][ct][q]);
            }
        }
}

// ---------------------------------------------------------------- MFMA GEMM, bf16 input (2 MFMAs)
__global__ __launch_bounds__(256, 6) void gemm_mfma_bf16_kernel(
    const unsigned short* __restrict__ H,
    const unsigned short* __restrict__ Thi, const unsigned short* __restrict__ Tlo,
    unsigned short* __restrict__ XLH, unsigned short* __restrict__ XRH, int nrows)
{
    __shared__ unsigned short sH[32 * 128];
    int t = threadIdx.x;
    int r0 = blockIdx.x * 32;

    #pragma unroll
    for (int i = 0; i < 2; ++i) {
        int idx = t + i * 256;
        int row = idx >> 4, chunk = idx & 15;
        int gr = min(r0 + row, nrows - 1);
        bf16x8 hv = *(const bf16x8*)&H[(size_t)gr * 128 + chunk * 8];
        int slot = chunk ^ (row & 7);
        *(bf16x8*)&sH[row * 128 + slot * 8] = hv;
    }
    __syncthreads();

    int w  = t >> 6;
    int l  = t & 63;
    int lr = l & 15;
    int lk = l >> 4;
    int cbase = w * 64;

    f32x4 acc[2][4];
    #pragma unroll
    for (int i = 0; i < 2; ++i)
        #pragma unroll
        for (int j = 0; j < 4; ++j)
            acc[i][j] = (f32x4){0.f, 0.f, 0.f, 0.f};

    #pragma unroll
    for (int k0 = 0; k0 < 128; k0 += 32) {
        bf16x8 ah[2];
        #pragma unroll
        for (int rt = 0; rt < 2; ++rt) {
            int row = rt * 16 + lr;
            int chunk = (k0 >> 3) + lk;
            int slot = chunk ^ (row & 7);
            ah[rt] = *(const bf16x8*)&sH[row * 128 + slot * 8];
        }
        int kc = (k0 >> 3) + lk;
        #pragma unroll
        for (int ct = 0; ct < 4; ++ct) {
            int c = cbase + ct * 16 + lr;
            size_t bidx = ((size_t)kc * 256 + c) * 8;
            bf16x8 bh = *(const bf16x8*)&Thi[bidx];
            bf16x8 bl = *(const bf16x8*)&Tlo[bidx];
            #pragma unroll
            for (int rt = 0; rt < 2; ++rt) {
                acc[rt][ct] = __builtin_amdgcn_mfma_f32_16x16x32_bf16(ah[rt], bh, acc[rt][ct], 0, 0, 0);
                acc[rt][ct] = __builtin_amdgcn_mfma_f32_16x16x32_bf16(ah[rt], bl, acc[rt][ct], 0, 0, 0);
            }
        }
    }

    unsigned short* OUT = (w < 2) ? XLH : XRH;
    int ccol0 = (cbase & 127);
    #pragma unroll
    for (int rt = 0; rt < 2; ++rt)
        #pragma unroll
        for (int ct = 0; ct < 4; ++ct) {
            int cc = ccol0 + ct * 16 + lr;
            #pragma unroll
            for (int q = 0; q < 4; ++q) {
                int r = r0 + rt * 16 + lk * 4 + q;
                if (r < nrows) OUT[(size_t)r * 128 + cc] = bf16_rne(acc[rt][ct][q]);
            }
        }
}

// ---------------------------------------------------------------- fused GATv2 attention + aggregation
__global__ __launch_bounds__(256) void gat_agg_kernel(
    const unsigned short* __restrict__ xlh, const unsigned short* __restrict__ xrh,
    const int* __restrict__ rowptr, const int* __restrict__ col,
    const float* __restrict__ eattr_perm,
    const float* __restrict__ We, const float* __restrict__ att, const float* __restrict__ bias,
    unsigned short* __restrict__ outh, float* __restrict__ outf, int N, int do_relu)
{
    int w = threadIdx.x >> 6;
    int lane = threadIdx.x & 63;
    int g = lane >> 4;
    int lg = lane & 15;
    int c0 = lg * 8;

    f32x2 at2[4], we2[4][4];
    #pragma unroll
    for (int p = 0; p < 4; ++p) at2[p] = (f32x2){att[c0 + 2 * p], att[c0 + 2 * p + 1]};
    #pragma unroll
    for (int k = 0; k < 4; ++k)
        #pragma unroll
        for (int p = 0; p < 4; ++p)
            we2[k][p] = (f32x2){We[k * 128 + c0 + 2 * p], We[k * 128 + c0 + 2 * p + 1]};

    int nbase = (blockIdx.x * 4 + w) * 4;
    if (nbase >= N) return;

    int rptr[5];
    #pragma unroll
    for (int j = 0; j < 5; ++j) rptr[j] = rowptr[min(nbase + j, N)];

    #pragma unroll 1
    for (int i = 0; i < 4; ++i) {
        int n = nbase + i;
        int nc = min(n, N - 1);

        f32x2 xr2[4];
        {
            bfpack xrp;
            xrp.v = *(const bf16x8*)&xrh[((size_t)nc << 7) + c0];
            #pragma unroll
            for (int p = 0; p < 4; ++p) {
                unsigned int u = xrp.u[p];
                xr2[p] = (f32x2){__uint_as_float(u << 16), __uint_as_float(u & 0xffff0000u)};
            }
        }

        int e0 = rptr[i], e1 = rptr[i + 1];
        int elim = e1 - 1;
        int iters = (e1 - e0 + 3) >> 2;

        float m = -INFINITY, den = 0.f;
        f32x2 acc2[4];
        #pragma unroll
        for (int p = 0; p < 4; ++p) acc2[p] = (f32x2){0.f, 0.f};

        auto process = [&](const float4& ea, const bfpack& xv, bool valid) {
            f32x2 xl2[4];
            #pragma unroll
            for (int p = 0; p < 4; ++p) {
                unsigned int u = xv.u[p];
                xl2[p] = (f32x2){__uint_as_float(u << 16), __uint_as_float(u & 0xffff0000u)};
            }
            f32x2 vd = (f32x2){0.f, 0.f};
            #pragma unroll
            for (int p = 0; p < 4; ++p) {
                f32x2 z = xl2[p] + xr2[p];
                z += splat2(ea.x) * we2[0][p];
                z += splat2(ea.y) * we2[1][p];
                z += splat2(ea.z) * we2[2][p];
                z += splat2(ea.w) * we2[3][p];
                f32x2 zs = splat2(SLOPE) * z;
                f32x2 lz = (f32x2){fmaxf(z.x, zs.x), fmaxf(z.y, zs.y)};
                vd += lz * at2[p];
            }
            float v = dpp_red16(vd.x + vd.y);
            v = valid ? v : -INFINITY;
            bool trig = (v - m > 8.0f);
            if (__any(trig)) {
                float mnew  = fmaxf(m, v);
                float scale = __expf(m - mnew);
                float wgt   = __expf(v - mnew);
                den = den * scale + wgt;
                #pragma unroll
                for (int p = 0; p < 4; ++p)
                    acc2[p] = acc2[p] * splat2(scale) + splat2(wgt) * xl2[p];
                m = mnew;
            } else {
                float wgt = __expf(v - m);
                den += wgt;
                #pragma unroll
                for (int p = 0; p < 4; ++p) acc2[p] += splat2(wgt) * xl2[p];
            }
        };

        int e = e0 + g;
        int ec = min(e, elim);
        int cc = col[ec];
        int cA = col[min(e + 4, elim)];
        float4 eaA = *(const float4*)&eattr_perm[(size_t)ec * 4];
        bfpack xlA;
        xlA.v = *(const bf16x8*)&xlh[((size_t)(unsigned)cc << 7) + c0];
        float4 eaB;
        bfpack xlB;

        int it = 0;
        for (; it + 2 <= iters; it += 2) {
            int enc = min(e + 4, elim);
            eaB = *(const float4*)&eattr_perm[(size_t)enc * 4];
            xlB.v = *(const bf16x8*)&xlh[((size_t)(unsigned)cA << 7) + c0];
            cA = col[min(e + 8, elim)];
            process(eaA, xlA, e < e1);
            e += 4;

            enc = min(e + 4, elim);
            eaA = *(const float4*)&eattr_perm[(size_t)enc * 4];
            xlA.v = *(const bf16x8*)&xlh[((size_t)(unsigned)cA << 7) + c0];
            cA = col[min(e + 8, elim)];
            process(eaB, xlB, e < e1);
            e += 4;
        }
        if (it < iters) process(eaA, xlA, e < e1);

        float M = fmaxf(m, __shfl_xor(m, 16));
        M = fmaxf(M, __shfl_xor(M, 32));
        float sc = __expf(m - M);
        float d2 = den * sc;
        d2 += __shfl_xor(d2, 16);
        d2 += __shfl_xor(d2, 32);
        float inv = 1.f / (d2 + 1e-16f);
        float o[8];
        #pragma unroll
        for (int p = 0; p < 4; ++p) {
            float ax = acc2[p].x * sc;
            float ay = acc2[p].y * sc;
            ax += __shfl_xor(ax, 16); ax += __shfl_xor(ax, 32);
            ay += __shfl_xor(ay, 16); ay += __shfl_xor(ay, 32);
            o[2 * p] = ax * inv;
            o[2 * p + 1] = ay * inv;
        }
        if (n < N && g == 0) {
            if (do_relu) {
                union { bf16x8 v; unsigned short u[8]; } ov;
                #pragma unroll
                for (int j = 0; j < 8; ++j)
                    ov.u[j] = bf16_rne(fmaxf(o[j] + bias[c0 + j], 0.f));
                *(bf16x8*)&outh[((size_t)n << 7) + c0] = ov.v;
            } else {
                #pragma unroll
                for (int j = 0; j < 8; ++j) o[j] += bias[c0 + j];
                *(float4*)&outf[((size_t)n << 7) + c0]     = make_float4(o[0], o[1], o[2], o[3]);
                *(float4*)&outf[((size_t)n << 7) + c0 + 4] = make_float4(o[4], o[5], o[6], o[7]);
            }
        }
    }
}

// ---------------------------------------------------------------- launch

static inline char* carve(char*& p, size_t bytes) {
    char* r = p;
    p += (bytes + 255) & ~(size_t)255;
    return r;
}

extern "C" void kernel_launch(void* const* d_in, const int* in_sizes, int n_in,
                              void* d_out, int out_size, void* d_ws, size_t ws_size,
                              hipStream_t stream)
{
    const int* edge_index = (const int*)d_in[0];
    int E = in_sizes[0] / 2;
    int N = in_sizes[2] / 128;
    const int* srcv = edge_index;
    const int* dstv = edge_index + E;
    const float* eattr = (const float*)d_in[1];
    const float* x = (const float*)d_in[2];

    char* p = (char*)d_ws;
    int*   gfill  = (int*)  carve(p, (size_t)512 * 4);
    int*   gbc    = (int*)  carve(p, (size_t)512 * 4);
    int*   bptr   = (int*)  carve(p, (size_t)512 * 4);
    int*   rowptr = (int*)  carve(p, (size_t)(N + 1) * 4);
    int*   col    = (int*)  carve(p, (size_t)(E + N) * 4);
    float* eperm  = (float*)carve(p, (size_t)(E + N) * 16);
    unsigned short* xlh = (unsigned short*)carve(p, (size_t)N * 256);
    unsigned short* xrh = (unsigned short*)carve(p, (size_t)N * 256);
    unsigned short* Thi = (unsigned short*)carve(p, (size_t)3 * 256 * 128 * 2);
    unsigned short* Tlo = (unsigned short*)carve(p, (size_t)3 * 256 * 128 * 2);
    unsigned long long* coarse = (unsigned long long*)xlh;
    unsigned short* hbuf = (unsigned short*)d_out;

    int sb = 1;
    while ((1 << sb) < N) ++sb;
    int nbuckets = (N + (1 << BSH) - 1) >> BSH;

    hipMemsetAsync(gfill, 0, (size_t)1024 * 4, stream);   // gfill + gbc (contiguous)

    bucket_count_kernel<<<(E + CH - 1) / CH, 256, 0, stream>>>(dstv, gbc, E);
    bucket_scan_kernel<<<1, 512, 0, stream>>>(gbc, bptr, nbuckets);
    bin_coarse_kernel<<<(E + CH - 1) / CH, 256, 0, stream>>>(
        srcv, dstv, bptr, gfill, coarse, E, nbuckets, sb);
    bin_fine_kernel<<<nbuckets, 256, 0, stream>>>(
        coarse, gbc, bptr, eattr, col, eperm, rowptr, N, E, nbuckets, sb);

    for (int li = 0; li < 3; ++li) {
        const float* Wl = (const float*)d_in[3 + 5 * li + 0];
        const float* Wr = (const float*)d_in[3 + 5 * li + 1];
        wprep_kernel<<<256, 128, 0, stream>>>(Wl, Wr,
                                              Thi + (size_t)li * 256 * 128,
                                              Tlo + (size_t)li * 256 * 128);
    }

    float* out = (float*)d_out;
    for (int li = 0; li < 3; ++li) {
        const float* Wep = (const float*)d_in[3 + 5 * li + 2];
        const float* atp = (const float*)d_in[3 + 5 * li + 3];
        const float* bp  = (const float*)d_in[3 + 5 * li + 4];
        if (li == 0) {
            gemm_mfma_kernel<<<(N + 31) / 32, 256, 0, stream>>>(
                x, Thi + (size_t)li * 256 * 128, Tlo + (size_t)li * 256 * 128, xlh, xrh, N);
        } else {
            gemm_mfma_bf16_kernel<<<(N + 31) / 32, 256, 0, stream>>>(
                hbuf, Thi + (size_t)li * 256 * 128, Tlo + (size_t)li * 256 * 128, xlh, xrh, N);
        }
        gat_agg_kernel<<<(N + 15) / 16, 256, 0, stream>>>(xlh, xrh, rowptr, col, eperm,
                                                          Wep, atp, bp, hbuf, out, N,
                                                          li < 2 ? 1 : 0);
    }
}

// Round 17
// 494.334 us; speedup vs baseline: 1.4708x; 1.0476x over previous
//
#include <hip/hip_runtime.h>
#include <hip/hip_bf16.h>
#include <cmath>

#define SLOPE 0.2f
#define CH 8192
#define BSH 8

typedef __attribute__((ext_vector_type(8))) short bf16x8;
typedef __attribute__((ext_vector_type(4))) float f32x4;
typedef __attribute__((ext_vector_type(2))) float f32x2;

union bfpack { bf16x8 v; unsigned int u[4]; };

__device__ __forceinline__ unsigned short bf16_rne(float x) {
    unsigned int b = __float_as_uint(x);
    b += 0x7FFFu + ((b >> 16) & 1u);
    return (unsigned short)(b >> 16);
}
__device__ __forceinline__ float bf16_tof(unsigned short h) {
    return __uint_as_float(((unsigned int)h) << 16);
}
__device__ __forceinline__ f32x2 splat2(float s) { return (f32x2){s, s}; }

// sum over 16-lane groups entirely in the VALU via DPP (no ds_bpermute)
__device__ __forceinline__ float dpp_red16(float x) {
    int y;
    y = __builtin_amdgcn_update_dpp(0, __float_as_int(x), 0xB1, 0xF, 0xF, true);
    x += __int_as_float(y);
    y = __builtin_amdgcn_update_dpp(0, __float_as_int(x), 0x4E, 0xF, 0xF, true);
    x += __int_as_float(y);
    y = __builtin_amdgcn_update_dpp(0, __float_as_int(x), 0x141, 0xF, 0xF, true);
    x += __int_as_float(y);
    y = __builtin_amdgcn_update_dpp(0, __float_as_int(x), 0x140, 0xF, 0xF, true);
    x += __int_as_float(y);
    return x;
}

// ---------------------------------------------------------------- preprocessing

__global__ __launch_bounds__(256) void bucket_count_kernel(
    const int* __restrict__ dstv, int* __restrict__ gbc, int E)
{
    __shared__ int lc[512];
    int t = threadIdx.x;
    for (int i = t; i < 512; i += 256) lc[i] = 0;
    __syncthreads();
    int base = blockIdx.x * CH;
    int count = min(CH, E - base);
    for (int j = t; j < count; j += 256)
        atomicAdd(&lc[dstv[base + j] >> BSH], 1);
    __syncthreads();
    for (int i = t; i < 512; i += 256)
        if (lc[i]) atomicAdd(&gbc[i], lc[i]);
}

__global__ void bucket_scan_kernel(const int* __restrict__ gbc, int* __restrict__ bptr, int nb)
{
    __shared__ int wsum[8];
    int t = threadIdx.x;
    int lane = t & 63, wv = t >> 6;
    int v = (t < nb) ? gbc[t] : 0;
    int incl = v;
    #pragma unroll
    for (int off = 1; off < 64; off <<= 1) {
        int u = __shfl_up(incl, off);
        if (lane >= off) incl += u;
    }
    if (lane == 63) wsum[wv] = incl;
    __syncthreads();
    int add = 0;
    for (int i = 0; i < wv; ++i) add += wsum[i];
    if (t < nb) bptr[t] = add + incl - v;
}

__global__ __launch_bounds__(256, 2) void bin_coarse_kernel(
    const int* __restrict__ srcv, const int* __restrict__ dstv,
    const int* __restrict__ bptr, int* __restrict__ gfill,
    unsigned long long* __restrict__ coarse, int E, int nbuckets, int sb)
{
    __shared__ unsigned long long recs[CH];
    __shared__ int lcount[512];
    __shared__ int loffs[512];
    __shared__ int gpos[512];
    __shared__ int cbase[512];
    int t = threadIdx.x;
    int base = blockIdx.x * CH;
    int count = min(CH, E - base);

    for (int b = t; b < 512; b += 256) lcount[b] = 0;
    __syncthreads();

    int rank[CH / 256];
    #pragma unroll
    for (int i = 0; i < CH / 256; ++i) {
        int j = i * 256 + t;
        if (j < count) {
            int d = dstv[base + j];
            rank[i] = atomicAdd(&lcount[d >> BSH], 1);
        }
    }
    __syncthreads();

    loffs[t] = lcount[t];
    loffs[t + 256] = lcount[t + 256];
    __syncthreads();
    for (int off = 1; off < 512; off <<= 1) {
        int i0 = t, i1 = t + 256;
        int v0 = (i0 >= off) ? loffs[i0 - off] : 0;
        int v1 = (i1 >= off) ? loffs[i1 - off] : 0;
        __syncthreads();
        loffs[i0] += v0;
        loffs[i1] += v1;
        __syncthreads();
    }

    #pragma unroll
    for (int i = 0; i < CH / 256; ++i) {
        int j = i * 256 + t;
        if (j < count) {
            int e = base + j;
            int d = dstv[e];
            int s = srcv[e];
            int b = d >> BSH;
            int slot = loffs[b] - lcount[b] + rank[i];
            recs[slot] = (unsigned long long)(unsigned)s
                       | ((unsigned long long)(unsigned)d << sb)
                       | ((unsigned long long)(unsigned)e << (2 * sb));
        }
    }
    __syncthreads();
    for (int b = t; b < nbuckets; b += 256) {
        int c = lcount[b];
        gpos[b] = c ? atomicAdd(&gfill[b], c) : 0;
        cbase[b] = bptr[b];
    }
    __syncthreads();
    int dmask = (1 << sb) - 1;
    for (int j = t; j < count; j += 256) {
        unsigned long long r = recs[j];
        int d = (int)((r >> sb) & dmask);
        int b = d >> BSH;
        int excl = loffs[b] - lcount[b];
        __builtin_nontemporal_store(r, &coarse[(size_t)cbase[b] + gpos[b] + (j - excl)]);
    }
}

__global__ __launch_bounds__(256) void bin_fine_kernel(
    const unsigned long long* __restrict__ coarse, const int* __restrict__ gbc,
    const int* __restrict__ bptr, const float* __restrict__ eattr,
    int* __restrict__ col, float* __restrict__ eattr_perm, int* __restrict__ rowptr,
    int N, int E, int nbuckets, int sb)
{
    __shared__ int ldeg[256];
    __shared__ int lrow[256];
    __shared__ int lfill[256];
    __shared__ float lsum[256][4];
    __shared__ int wpart[4];
    int b = blockIdx.x;
    int t = threadIdx.x;
    int n0 = b << BSH;
    ldeg[t] = 0;
    lfill[t] = 0;
    #pragma unroll
    for (int k = 0; k < 4; ++k) lsum[t][k] = 0.f;
    __syncthreads();
    int cb = bptr[b];
    int cnt = gbc[b];
    int dmask = (1 << sb) - 1;
    for (int j = t; j < cnt; j += 256) {
        unsigned long long r = coarse[(size_t)cb + j];
        int d = (int)((r >> sb) & dmask);
        atomicAdd(&ldeg[d & ((1 << BSH) - 1)], 1);
    }
    __syncthreads();
    int nvalid = min(256, N - n0);
    int v = (t < nvalid) ? (ldeg[t] + 1) : 0;
    int lane = t & 63, wv = t >> 6;
    int incl = v;
    #pragma unroll
    for (int off = 1; off < 64; off <<= 1) {
        int u = __shfl_up(incl, off);
        if (lane >= off) incl += u;
    }
    if (lane == 63) wpart[wv] = incl;
    __syncthreads();
    int wadd = 0;
    for (int i = 0; i < wv; ++i) wadd += wpart[i];
    int myrow = cb + n0 + wadd + incl - v;
    lrow[t] = myrow;
    if (t < nvalid) rowptr[n0 + t] = myrow;
    if (b == nbuckets - 1 && t == 0) rowptr[N] = E + N;
    __syncthreads();
    for (int j = t; j < cnt; j += 256) {
        unsigned long long r = coarse[(size_t)cb + j];
        int s = (int)(r & dmask);
        int d = (int)((r >> sb) & dmask);
        unsigned e = (unsigned)(r >> (2 * sb));
        int local = d & ((1 << BSH) - 1);
        int pos = lrow[local] + atomicAdd(&lfill[local], 1);
        float4 ea = *(const float4*)&eattr[(size_t)e * 4];
        col[pos] = s;
        *(float4*)&eattr_perm[(size_t)pos * 4] = ea;
        atomicAdd(&lsum[local][0], ea.x);
        atomicAdd(&lsum[local][1], ea.y);
        atomicAdd(&lsum[local][2], ea.z);
        atomicAdd(&lsum[local][3], ea.w);
    }
    __syncthreads();
    if (t < nvalid) {
        int dg = ldeg[t];
        int pos = lrow[t] + dg;
        float inv = 1.f / fmaxf((float)dg, 1.f);
        col[pos] = n0 + t;
        *(float4*)&eattr_perm[(size_t)pos * 4] =
            make_float4(lsum[t][0] * inv, lsum[t][1] * inv, lsum[t][2] * inv, lsum[t][3] * inv);
    }
}

// W prep, all 3 layers in one launch: blockIdx = li*256 + c.
// element (k,c) stored k-chunk-major: T[((k>>3)*256 + c)*8 + (k&7)].
__global__ __launch_bounds__(128) void wprep_kernel(
    const float* __restrict__ Wl0, const float* __restrict__ Wr0,
    const float* __restrict__ Wl1, const float* __restrict__ Wr1,
    const float* __restrict__ Wl2, const float* __restrict__ Wr2,
    unsigned short* __restrict__ Thi, unsigned short* __restrict__ Tlo)
{
    int li = blockIdx.x >> 8;
    int c = blockIdx.x & 255;
    int k = threadIdx.x;
    const float* W = (li == 0) ? ((c < 128) ? Wl0 : Wr0)
                   : (li == 1) ? ((c < 128) ? Wl1 : Wr1)
                               : ((c < 128) ? Wl2 : Wr2);
    float v = W[(size_t)k * 128 + (c & 127)];
    unsigned short h = bf16_rne(v);
    float lo = v - bf16_tof(h);
    size_t idx = (size_t)li * 256 * 128 + ((size_t)(k >> 3) * 256 + c) * 8 + (k & 7);
    Thi[idx] = h;
    Tlo[idx] = bf16_rne(lo);
}

// ---------------------------------------------------------------- MFMA GEMM, fp32 input (bf16x3, 32-row tile)
__global__ __launch_bounds__(256, 4) void gemm_mfma_kernel(
    const float* __restrict__ H,
    const unsigned short* __restrict__ Thi, const unsigned short* __restrict__ Tlo,
    unsigned short* __restrict__ XLH, unsigned short* __restrict__ XRH, int nrows)
{
    __shared__ unsigned short sHi[32 * 128];
    __shared__ unsigned short sLo[32 * 128];
    int t = threadIdx.x;
    int r0 = blockIdx.x * 32;

    #pragma unroll
    for (int i = 0; i < 2; ++i) {
        int idx = t + i * 256;
        int row = idx >> 4, chunk = idx & 15;
        int gr = min(r0 + row, nrows - 1);
        float4 a = *(const float4*)&H[(size_t)gr * 128 + chunk * 8];
        float4 b = *(const float4*)&H[(size_t)gr * 128 + chunk * 8 + 4];
        float v[8] = {a.x, a.y, a.z, a.w, b.x, b.y, b.z, b.w};
        union { bf16x8 v; unsigned short u[8]; } hv, lv;
        #pragma unroll
        for (int j = 0; j < 8; ++j) {
            unsigned short h = bf16_rne(v[j]);
            hv.u[j] = h;
            lv.u[j] = bf16_rne(v[j] - bf16_tof(h));
        }
        int slot = chunk ^ (row & 7);
        *(bf16x8*)&sHi[row * 128 + slot * 8] = hv.v;
        *(bf16x8*)&sLo[row * 128 + slot * 8] = lv.v;
    }
    __syncthreads();

    int w  = t >> 6;
    int l  = t & 63;
    int lr = l & 15;
    int lk = l >> 4;
    int cbase = w * 64;

    f32x4 acc[2][4];
    #pragma unroll
    for (int i = 0; i < 2; ++i)
        #pragma unroll
        for (int j = 0; j < 4; ++j)
            acc[i][j] = (f32x4){0.f, 0.f, 0.f, 0.f};

    #pragma unroll
    for (int k0 = 0; k0 < 128; k0 += 32) {
        bf16x8 ah[2], al[2];
        #pragma unroll
        for (int rt = 0; rt < 2; ++rt) {
            int row = rt * 16 + lr;
            int chunk = (k0 >> 3) + lk;
            int slot = chunk ^ (row & 7);
            ah[rt] = *(const bf16x8*)&sHi[row * 128 + slot * 8];
            al[rt] = *(const bf16x8*)&sLo[row * 128 + slot * 8];
        }
        int kc = (k0 >> 3) + lk;
        #pragma unroll
        for (int ct = 0; ct < 4; ++ct) {
            int c = cbase + ct * 16 + lr;
            size_t bidx = ((size_t)kc * 256 + c) * 8;
            bf16x8 bh = *(const bf16x8*)&Thi[bidx];
            bf16x8 bl = *(const bf16x8*)&Tlo[bidx];
            #pragma unroll
            for (int rt = 0; rt < 2; ++rt) {
                acc[rt][ct] = __builtin_amdgcn_mfma_f32_16x16x32_bf16(ah[rt], bh, acc[rt][ct], 0, 0, 0);
                acc[rt][ct] = __builtin_amdgcn_mfma_f32_16x16x32_bf16(al[rt], bh, acc[rt][ct], 0, 0, 0);
                acc[rt][ct] = __builtin_amdgcn_mfma_f32_16x16x32_bf16(ah[rt], bl, acc[rt][ct], 0, 0, 0);
            }
        }
    }

    unsigned short* OUT = (w < 2) ? XLH : XRH;
    int ccol0 = (cbase & 127);
    #pragma unroll
    for (int rt = 0; rt < 2; ++rt)
        #pragma unroll
        for (int ct = 0; ct < 4; ++ct) {
            int cc = ccol0 + ct * 16 + lr;
            #pragma unroll
            for (int q = 0; q < 4; ++q) {
                int r = r0 + rt * 16 + lk * 4 + q;
                if (r < nrows) OUT[(size_t)r * 128 + cc] = bf16_rne(acc[rt][ct][q]);
            }
        }
}

// ---------------------------------------------------------------- MFMA GEMM, bf16 input (2 MFMAs, 64-row tile)
// 64-row tile halves per-row T re-reads (T read once per block from L2).
__global__ __launch_bounds__(256, 4) void gemm_mfma_bf16_kernel(
    const unsigned short* __restrict__ H,
    const unsigned short* __restrict__ Thi, const unsigned short* __restrict__ Tlo,
    unsigned short* __restrict__ XLH, unsigned short* __restrict__ XRH, int nrows)
{
    __shared__ unsigned short sH[64 * 128];
    int t = threadIdx.x;
    int r0 = blockIdx.x * 64;

    #pragma unroll
    for (int i = 0; i < 4; ++i) {
        int idx = t + i * 256;           // 1024 = 64 rows * 16 chunks
        int row = idx >> 4, chunk = idx & 15;
        int gr = min(r0 + row, nrows - 1);
        bf16x8 hv = *(const bf16x8*)&H[(size_t)gr * 128 + chunk * 8];
        int slot = chunk ^ (row & 7);
        *(bf16x8*)&sH[row * 128 + slot * 8] = hv;
    }
    __syncthreads();

    int w  = t >> 6;
    int l  = t & 63;
    int lr = l & 15;
    int lk = l >> 4;
    int cbase = w * 64;

    f32x4 acc[4][4];
    #pragma unroll
    for (int i = 0; i < 4; ++i)
        #pragma unroll
        for (int j = 0; j < 4; ++j)
            acc[i][j] = (f32x4){0.f, 0.f, 0.f, 0.f};

    #pragma unroll
    for (int k0 = 0; k0 < 128; k0 += 32) {
        bf16x8 ah[4];
        #pragma unroll
        for (int rt = 0; rt < 4; ++rt) {
            int row = rt * 16 + lr;
            int chunk = (k0 >> 3) + lk;
            int slot = chunk ^ (row & 7);
            ah[rt] = *(const bf16x8*)&sH[row * 128 + slot * 8];
        }
        int kc = (k0 >> 3) + lk;
        #pragma unroll
        for (int ct = 0; ct < 4; ++ct) {
            int c = cbase + ct * 16 + lr;
            size_t bidx = ((size_t)kc * 256 + c) * 8;
            bf16x8 bh = *(const bf16x8*)&Thi[bidx];
            bf16x8 bl = *(const bf16x8*)&Tlo[bidx];
            #pragma unroll
            for (int rt = 0; rt < 4; ++rt) {
                acc[rt][ct] = __builtin_amdgcn_mfma_f32_16x16x32_bf16(ah[rt], bh, acc[rt][ct], 0, 0, 0);
                acc[rt][ct] = __builtin_amdgcn_mfma_f32_16x16x32_bf16(ah[rt], bl, acc[rt][ct], 0, 0, 0);
            }
        }
    }

    unsigned short* OUT = (w < 2) ? XLH : XRH;
    int ccol0 = (cbase & 127);
    #pragma unroll
    for (int rt = 0; rt < 4; ++rt)
        #pragma unroll
        for (int ct = 0; ct < 4; ++ct) {
            int cc = ccol0 + ct * 16 + lr;
            #pragma unroll
            for (int q = 0; q < 4; ++q) {
                int r = r0 + rt * 16 + lk * 4 + q;
                if (r < nrows) OUT[(size_t)r * 128 + cc] = bf16_rne(acc[rt][ct][q]);
            }
        }
}

// ---------------------------------------------------------------- fused GATv2 attention + aggregation
// 1-wave blocks (4 nodes/wave): waves retire independently — no block-tail
// holding scheduler slots. 4 edges in flight (16 lanes/edge, 8 ch/lane).
__global__ __launch_bounds__(64) void gat_agg_kernel(
    const unsigned short* __restrict__ xlh, const unsigned short* __restrict__ xrh,
    const int* __restrict__ rowptr, const int* __restrict__ col,
    const float* __restrict__ eattr_perm,
    const float* __restrict__ We, const float* __restrict__ att, const float* __restrict__ bias,
    unsigned short* __restrict__ outh, float* __restrict__ outf, int N, int do_relu)
{
    int lane = threadIdx.x & 63;
    int g = lane >> 4;
    int lg = lane & 15;
    int c0 = lg * 8;

    f32x2 at2[4], we2[4][4];
    #pragma unroll
    for (int p = 0; p < 4; ++p) at2[p] = (f32x2){att[c0 + 2 * p], att[c0 + 2 * p + 1]};
    #pragma unroll
    for (int k = 0; k < 4; ++k)
        #pragma unroll
        for (int p = 0; p < 4; ++p)
            we2[k][p] = (f32x2){We[k * 128 + c0 + 2 * p], We[k * 128 + c0 + 2 * p + 1]};

    int nbase = blockIdx.x * 4;
    if (nbase >= N) return;

    int rptr[5];
    #pragma unroll
    for (int j = 0; j < 5; ++j) rptr[j] = rowptr[min(nbase + j, N)];

    #pragma unroll 1
    for (int i = 0; i < 4; ++i) {
        int n = nbase + i;
        int nc = min(n, N - 1);

        f32x2 xr2[4];
        {
            bfpack xrp;
            xrp.v = *(const bf16x8*)&xrh[((size_t)nc << 7) + c0];
            #pragma unroll
            for (int p = 0; p < 4; ++p) {
                unsigned int u = xrp.u[p];
                xr2[p] = (f32x2){__uint_as_float(u << 16), __uint_as_float(u & 0xffff0000u)};
            }
        }

        int e0 = rptr[i], e1 = rptr[i + 1];
        int elim = e1 - 1;
        int iters = (e1 - e0 + 3) >> 2;

        float m = -INFINITY, den = 0.f;
        f32x2 acc2[4];
        #pragma unroll
        for (int p = 0; p < 4; ++p) acc2[p] = (f32x2){0.f, 0.f};

        auto process = [&](const float4& ea, const bfpack& xv, bool valid) {
            f32x2 xl2[4];
            #pragma unroll
            for (int p = 0; p < 4; ++p) {
                unsigned int u = xv.u[p];
                xl2[p] = (f32x2){__uint_as_float(u << 16), __uint_as_float(u & 0xffff0000u)};
            }
            f32x2 vd = (f32x2){0.f, 0.f};
            #pragma unroll
            for (int p = 0; p < 4; ++p) {
                f32x2 z = xl2[p] + xr2[p];
                z += splat2(ea.x) * we2[0][p];
                z += splat2(ea.y) * we2[1][p];
                z += splat2(ea.z) * we2[2][p];
                z += splat2(ea.w) * we2[3][p];
                f32x2 zs = splat2(SLOPE) * z;
                f32x2 lz = (f32x2){fmaxf(z.x, zs.x), fmaxf(z.y, zs.y)};
                vd += lz * at2[p];
            }
            float v = dpp_red16(vd.x + vd.y);
            v = valid ? v : -INFINITY;
            bool trig = (v - m > 8.0f);
            if (__any(trig)) {
                float mnew  = fmaxf(m, v);
                float scale = __expf(m - mnew);
                float wgt   = __expf(v - mnew);
                den = den * scale + wgt;
                #pragma unroll
                for (int p = 0; p < 4; ++p)
                    acc2[p] = acc2[p] * splat2(scale) + splat2(wgt) * xl2[p];
                m = mnew;
            } else {
                float wgt = __expf(v - m);
                den += wgt;
                #pragma unroll
                for (int p = 0; p < 4; ++p) acc2[p] += splat2(wgt) * xl2[p];
            }
        };

        int e = e0 + g;
        int ec = min(e, elim);
        int cc = col[ec];
        int cA = col[min(e + 4, elim)];
        float4 eaA = *(const float4*)&eattr_perm[(size_t)ec * 4];
        bfpack xlA;
        xlA.v = *(const bf16x8*)&xlh[((size_t)(unsigned)cc << 7) + c0];
        float4 eaB;
        bfpack xlB;

        int it = 0;
        for (; it + 2 <= iters; it += 2) {
            int enc = min(e + 4, elim);
            eaB = *(const float4*)&eattr_perm[(size_t)enc * 4];
            xlB.v = *(const bf16x8*)&xlh[((size_t)(unsigned)cA << 7) + c0];
            cA = col[min(e + 8, elim)];
            process(eaA, xlA, e < e1);
            e += 4;

            enc = min(e + 4, elim);
            eaA = *(const float4*)&eattr_perm[(size_t)enc * 4];
            xlA.v = *(const bf16x8*)&xlh[((size_t)(unsigned)cA << 7) + c0];
            cA = col[min(e + 8, elim)];
            process(eaB, xlB, e < e1);
            e += 4;
        }
        if (it < iters) process(eaA, xlA, e < e1);

        float M = fmaxf(m, __shfl_xor(m, 16));
        M = fmaxf(M, __shfl_xor(M, 32));
        float sc = __expf(m - M);
        float d2 = den * sc;
        d2 += __shfl_xor(d2, 16);
        d2 += __shfl_xor(d2, 32);
        float inv = 1.f / (d2 + 1e-16f);
        float o[8];
        #pragma unroll
        for (int p = 0; p < 4; ++p) {
            float ax = acc2[p].x * sc;
            float ay = acc2[p].y * sc;
            ax += __shfl_xor(ax, 16); ax += __shfl_xor(ax, 32);
            ay += __shfl_xor(ay, 16); ay += __shfl_xor(ay, 32);
            o[2 * p] = ax * inv;
            o[2 * p + 1] = ay * inv;
        }
        if (n < N && g == 0) {
            if (do_relu) {
                union { bf16x8 v; unsigned short u[8]; } ov;
                #pragma unroll
                for (int j = 0; j < 8; ++j)
                    ov.u[j] = bf16_rne(fmaxf(o[j] + bias[c0 + j], 0.f));
                *(bf16x8*)&outh[((size_t)n << 7) + c0] = ov.v;
            } else {
                #pragma unroll
                for (int j = 0; j < 8; ++j) o[j] += bias[c0 + j];
                *(float4*)&outf[((size_t)n << 7) + c0]     = make_float4(o[0], o[1], o[2], o[3]);
                *(float4*)&outf[((size_t)n << 7) + c0 + 4] = make_float4(o[4], o[5], o[6], o[7]);
            }
        }
    }
}

// ---------------------------------------------------------------- launch

static inline char* carve(char*& p, size_t bytes) {
    char* r = p;
    p += (bytes + 255) & ~(size_t)255;
    return r;
}

extern "C" void kernel_launch(void* const* d_in, const int* in_sizes, int n_in,
                              void* d_out, int out_size, void* d_ws, size_t ws_size,
                              hipStream_t stream)
{
    const int* edge_index = (const int*)d_in[0];
    int E = in_sizes[0] / 2;
    int N = in_sizes[2] / 128;
    const int* srcv = edge_index;
    const int* dstv = edge_index + E;
    const float* eattr = (const float*)d_in[1];
    const float* x = (const float*)d_in[2];

    char* p = (char*)d_ws;
    int*   gfill  = (int*)  carve(p, (size_t)512 * 4);
    int*   gbc    = (int*)  carve(p, (size_t)512 * 4);
    int*   bptr   = (int*)  carve(p, (size_t)512 * 4);
    int*   rowptr = (int*)  carve(p, (size_t)(N + 1) * 4);
    int*   col    = (int*)  carve(p, (size_t)(E + N) * 4);
    float* eperm  = (float*)carve(p, (size_t)(E + N) * 16);
    unsigned short* xlh = (unsigned short*)carve(p, (size_t)N * 256);
    unsigned short* xrh = (unsigned short*)carve(p, (size_t)N * 256);
    unsigned short* Thi = (unsigned short*)carve(p, (size_t)3 * 256 * 128 * 2);
    unsigned short* Tlo = (unsigned short*)carve(p, (size_t)3 * 256 * 128 * 2);
    unsigned long long* coarse = (unsigned long long*)xlh;
    unsigned short* hbuf = (unsigned short*)d_out;

    int sb = 1;
    while ((1 << sb) < N) ++sb;
    int nbuckets = (N + (1 << BSH) - 1) >> BSH;

    hipMemsetAsync(gfill, 0, (size_t)1024 * 4, stream);   // gfill + gbc (contiguous)

    bucket_count_kernel<<<(E + CH - 1) / CH, 256, 0, stream>>>(dstv, gbc, E);
    bucket_scan_kernel<<<1, 512, 0, stream>>>(gbc, bptr, nbuckets);
    bin_coarse_kernel<<<(E + CH - 1) / CH, 256, 0, stream>>>(
        srcv, dstv, bptr, gfill, coarse, E, nbuckets, sb);
    bin_fine_kernel<<<nbuckets, 256, 0, stream>>>(
        coarse, gbc, bptr, eattr, col, eperm, rowptr, N, E, nbuckets, sb);

    wprep_kernel<<<768, 128, 0, stream>>>(
        (const float*)d_in[3], (const float*)d_in[4],
        (const float*)d_in[8], (const float*)d_in[9],
        (const float*)d_in[13], (const float*)d_in[14], Thi, Tlo);

    float* out = (float*)d_out;
    for (int li = 0; li < 3; ++li) {
        const float* Wep = (const float*)d_in[3 + 5 * li + 2];
        const float* atp = (const float*)d_in[3 + 5 * li + 3];
        const float* bp  = (const float*)d_in[3 + 5 * li + 4];
        if (li == 0) {
            gemm_mfma_kernel<<<(N + 31) / 32, 256, 0, stream>>>(
                x, Thi + (size_t)li * 256 * 128, Tlo + (size_t)li * 256 * 128, xlh, xrh, N);
        } else {
            gemm_mfma_bf16_kernel<<<(N + 63) / 64, 256, 0, stream>>>(
                hbuf, Thi + (size_t)li * 256 * 128, Tlo + (size_t)li * 256 * 128, xlh, xrh, N);
        }
        gat_agg_kernel<<<(N + 3) / 4, 64, 0, stream>>>(xlh, xrh, rowptr, col, eperm,
                                                       Wep, atp, bp, hbuf, out, N,
                                                       li < 2 ? 1 : 0);
    }
}